// Round 2
// baseline (905.273 us; speedup 1.0000x reference)
//
#include <hip/hip_runtime.h>
#include <hip/hip_bf16.h>
#include <stdint.h>

typedef __hip_bfloat16 bf16;
typedef __attribute__((ext_vector_type(8))) __bf16 bf16x8;
typedef __attribute__((ext_vector_type(4))) float f32x4;

#define D_MODEL 1024
#define NHEAD   16
#define HDIM    64
#define DFF     4096
#define BATCH   16
#define SEQ     512
#define MROWS   (BATCH*SEQ)   // 8192

__device__ __forceinline__ float b2f_bits(unsigned short u) {
    return __uint_as_float(((unsigned)u) << 16);
}
__device__ __forceinline__ bf16 f2b(float v) { return __float2bfloat16(v); }
__device__ __forceinline__ unsigned short f2b_bits(float v) {
    bf16 t = __float2bfloat16(v);
    return *(unsigned short*)&t;
}
// async global->LDS, 16B per lane (dest must be linear base + lane*16)
__device__ __forceinline__ void gll16(void* lds, const void* gsrc) {
    __builtin_amdgcn_global_load_lds(
        (const __attribute__((address_space(1))) unsigned*)gsrc,
        (__attribute__((address_space(3))) unsigned*)lds,
        16, 0, 0);
}

// ---------------------------------------------------------------------------
// fp32 -> bf16 weight conversion (n multiple of 4; grid covers exactly n/4)
// ---------------------------------------------------------------------------
__global__ __launch_bounds__(256)
void cvt_kernel(const float* __restrict__ in, bf16* __restrict__ out, int n)
{
    int i = (blockIdx.x * 256 + threadIdx.x) * 4;
    if (i >= n) return;
    float4 f = *(const float4*)(in + i);
    ushort4 o;
    o.x = f2b_bits(f.x); o.y = f2b_bits(f.y);
    o.z = f2b_bits(f.z); o.w = f2b_bits(f.w);
    *(ushort4*)((unsigned short*)out + i) = o;
}

// ---------------------------------------------------------------------------
// LayerNorm: fp32 in, bf16 out. One block (256 threads) per row of 1024.
// ---------------------------------------------------------------------------
__global__ __launch_bounds__(256)
void ln_kernel(const float* __restrict__ xin, const float* __restrict__ w,
               const float* __restrict__ b, bf16* __restrict__ out)
{
    int row  = blockIdx.x;
    int t    = threadIdx.x;
    int lane = t & 63, wv = t >> 6;
    int col  = t * 4;

    float4 f = *(const float4*)(xin + (size_t)row * D_MODEL + col);
    float v[4] = {f.x, f.y, f.z, f.w};

    float s  = v[0] + v[1] + v[2] + v[3];
    float ss = v[0]*v[0] + v[1]*v[1] + v[2]*v[2] + v[3]*v[3];
    #pragma unroll
    for (int m = 1; m < 64; m <<= 1) {
        s  += __shfl_xor(s,  m, 64);
        ss += __shfl_xor(ss, m, 64);
    }
    __shared__ float rs0[4], rs1[4];
    if (lane == 0) { rs0[wv] = s; rs1[wv] = ss; }
    __syncthreads();
    s  = rs0[0] + rs0[1] + rs0[2] + rs0[3];
    ss = rs1[0] + rs1[1] + rs1[2] + rs1[3];

    float mu  = s * (1.0f / D_MODEL);
    float var = ss * (1.0f / D_MODEL) - mu * mu;
    float rs  = rsqrtf(var + 1e-5f);

    float4 wf = *(const float4*)(w + col);
    float4 bf = *(const float4*)(b + col);
    ushort4 o;
    o.x = f2b_bits((v[0]-mu)*rs*wf.x + bf.x);
    o.y = f2b_bits((v[1]-mu)*rs*wf.y + bf.y);
    o.z = f2b_bits((v[2]-mu)*rs*wf.z + bf.z);
    o.w = f2b_bits((v[3]-mu)*rs*wf.w + bf.w);
    *(ushort4*)((unsigned short*)out + (size_t)row * D_MODEL + col) = o;
}

// ---------------------------------------------------------------------------
// MFMA GEMM: C[M,N] = A[M,K] * Bw[N,K]^T + bias (fp32). Epilogues:
//   EPI 0: bias -> out            EPI 1: bias + exact GELU -> out
//   EPI 2: bias + fp32 residual -> out
//   EPI 3: bias -> scatter bf16 Q (b,h,s,e) / K (b,h,s,e) / VT (b,h,e,s)
// OUT_B16: store bf16 (internal buffers) vs fp32 (x1 / d_out).
// 128x128 tile, 256 threads (4 waves 2x2), wave = 4x4 mfma_f32_16x16x32_bf16.
// Staging via global_load_lds width=16 (m97 structure): dest = lds + t*16,
// linear [128 rows][32 cols] layout == read layout; 2 barriers per K-step.
// C/D mapping (m89/m91 verified): col = lane&15, row = (lane>>4)*4 + reg.
// M,N multiples of 128; K multiple of 32.
// ---------------------------------------------------------------------------
template<int EPI, bool OUT_B16>
__global__ __launch_bounds__(256)
void gemm_bt(const bf16* __restrict__ A, const bf16* __restrict__ Bw,
             const float* __restrict__ bias, const float* __restrict__ resid,
             void* __restrict__ Cout, bf16* __restrict__ qb,
             bf16* __restrict__ ktb, bf16* __restrict__ vb,
             int M, int N, int K)
{
    int t    = threadIdx.x;
    int lane = t & 63, w = t >> 6;
    int wm   = w & 1,  wn = w >> 1;
    int q    = lane >> 4, r = lane & 15;
    int mb   = blockIdx.y * 128, nb = blockIdx.x * 128;

    __shared__ __bf16 As[128 * 32];
    __shared__ __bf16 Bs[128 * 32];

    f32x4 acc[4][4] = {};

    const char* Ag = (const char*)((const unsigned short*)A + (size_t)mb * K);
    const char* Bg = (const char*)((const unsigned short*)Bw + (size_t)nb * K);

    int ar0 = t >> 2,  ac0 = (t & 3) << 3;   // row, elem-col of this thread's 16B

    for (int k0 = 0; k0 < K; k0 += 32) {
        __syncthreads();   // readers of previous tile done
        size_t off0 = ((size_t)ar0 * K + k0 + ac0) * 2;
        size_t off1 = off0 + (size_t)64 * K * 2;       // +64 rows
        gll16((char*)As + t * 16,        Ag + off0);
        gll16((char*)As + 4096 + t * 16, Ag + off1);
        gll16((char*)Bs + t * 16,        Bg + off0);
        gll16((char*)Bs + 4096 + t * 16, Bg + off1);
        __syncthreads();   // drains vmcnt -> LDS data visible

        bf16x8 af[4], bfr[4];
        #pragma unroll
        for (int i = 0; i < 4; i++)
            af[i] = *(const bf16x8*)(As + (wm * 64 + i * 16 + r) * 32 + q * 8);
        #pragma unroll
        for (int j = 0; j < 4; j++)
            bfr[j] = *(const bf16x8*)(Bs + (wn * 64 + j * 16 + r) * 32 + q * 8);
        #pragma unroll
        for (int i = 0; i < 4; i++)
            #pragma unroll
            for (int j = 0; j < 4; j++)
                acc[i][j] = __builtin_amdgcn_mfma_f32_16x16x32_bf16(af[i], bfr[j], acc[i][j], 0, 0, 0);
    }

    #pragma unroll
    for (int j = 0; j < 4; j++) {
        int n = nb + wn * 64 + j * 16 + r;
        float bv = bias[n];
        #pragma unroll
        for (int i = 0; i < 4; i++) {
            int mbase = mb + wm * 64 + i * 16 + q * 4;
            #pragma unroll
            for (int rr = 0; rr < 4; rr++) {
                int m = mbase + rr;
                float v = acc[i][j][rr] + bv;
                if (EPI == 1) v = 0.5f * v * (1.0f + erff(v * 0.70710678118654752f));
                if (EPI == 2) v += resid[(size_t)m * N + n];
                if (EPI == 3) {
                    int sect = n >> 10;
                    int h = (n >> 6) & 15;
                    int e = n & 63;
                    int bi = m >> 9, s = m & 511;
                    size_t bh = (size_t)bi * NHEAD + h;
                    bf16 val = f2b(v);
                    if (sect == 0)      qb[((bh * SEQ + s) << 6) + e] = val;
                    else if (sect == 1) ktb[((bh * SEQ + s) << 6) + e] = val;  // K rows
                    else                vb[((bh * HDIM + e) << 9) + s] = val;  // V^T
                } else {
                    if (OUT_B16) ((bf16*)Cout)[(size_t)m * N + n] = f2b(v);
                    else         ((float*)Cout)[(size_t)m * N + n] = v;
                }
            }
        }
    }
}

// ---------------------------------------------------------------------------
// MFMA attention. Grid (8 q-tiles, 256 bh) -> XCD-swizzled so each XCD owns a
// contiguous 32-bh chunk (q-tiles of one bh consecutive on one XCD: K/VT stay
// L2-resident, ~55 MB compulsory fetch instead of 140 MB).
// 256 thr = 4 waves; wave = 16 q-rows x 512 keys. Q,K (b,h,s,64); VT (b,h,64,s).
// P-LDS halved to [64][256] (32 KiB, wave-private rows, XOR-swizzled): PV runs
// in two 256-key passes reusing the buffer -> LDS 36.9 KB -> 4 blocks/CU.
// C/D: col=lane&15, row=(lane>>4)*4+reg (m89/m91 verified).
// ---------------------------------------------------------------------------
__global__ __launch_bounds__(256, 4)
void attn_mfma(const bf16* __restrict__ Q, const bf16* __restrict__ K,
               const bf16* __restrict__ VT, const float* __restrict__ relb,
               bf16* __restrict__ out)
{
    // XCD swizzle: linear id L, xcd = L%8 (m09 round-robin); each xcd gets
    // bh in [xcd*32, xcd*32+32), q-tile fastest.
    int L   = blockIdx.x + (blockIdx.y << 3);   // grid (8,256) -> L in [0,2048)
    int xcd = L & 7, jj = L >> 3;
    int bh  = xcd * 32 + (jj >> 3);
    int q0  = (jj & 7) * 64;
    int b   = bh >> 4, h = bh & 15;
    int t = threadIdx.x, lane = t & 63, w = t >> 6;
    int l15 = lane & 15, l4 = lane >> 4;

    __shared__ __bf16 Pls[64 * 256];   // 32 KiB, swizzled, wave-private rows
    __shared__ float  rbs[1024];       // rel-bias row for this head

    const float* rb = relb + (size_t)h * (2 * SEQ - 1);
    for (int i = t; i < 2 * SEQ - 1; i += 256) rbs[i] = rb[i];
    __syncthreads();

    // ---- QK^T: 32 key-tiles of 16, 2 MFMAs each ----
    const unsigned short* Qp = (const unsigned short*)Q
        + (((size_t)bh * SEQ + q0 + w * 16 + l15) << 6) + l4 * 8;
    bf16x8 qf0 = *(const bf16x8*)Qp;
    bf16x8 qf1 = *(const bf16x8*)(Qp + 32);

    const unsigned short* Kp = (const unsigned short*)K
        + (((size_t)bh * SEQ + l15) << 6) + l4 * 8;

    f32x4 sc[32];
    #pragma unroll
    for (int kt = 0; kt < 32; kt++) {
        const unsigned short* kp = Kp + ((size_t)kt << 10);  // 16 rows * 64
        bf16x8 kf0 = *(const bf16x8*)kp;
        bf16x8 kf1 = *(const bf16x8*)(kp + 32);
        f32x4 a = {};
        a = __builtin_amdgcn_mfma_f32_16x16x32_bf16(qf0, kf0, a, 0, 0, 0);
        a = __builtin_amdgcn_mfma_f32_16x16x32_bf16(qf1, kf1, a, 0, 0, 0);
        sc[kt] = a;
    }

    // ---- scale + bias + row max ----
    int qbase = q0 + w * 16 + l4 * 4;          // + reg = this lane's rows
    float mx[4] = {-1e30f, -1e30f, -1e30f, -1e30f};
    #pragma unroll
    for (int kt = 0; kt < 32; kt++) {
        int relbase = qbase - (kt * 16 + l15) + (SEQ - 1);
        #pragma unroll
        for (int reg = 0; reg < 4; reg++) {
            float v = sc[kt][reg] * 0.125f + rbs[relbase + reg];
            sc[kt][reg] = v;
            mx[reg] = fmaxf(mx[reg], v);
        }
    }
    #pragma unroll
    for (int m = 1; m < 16; m <<= 1)
        #pragma unroll
        for (int reg = 0; reg < 4; reg++)
            mx[reg] = fmaxf(mx[reg], __shfl_xor(mx[reg], m, 64));

    // ---- two 256-key passes: exp+pack -> swizzled LDS, then PV MFMAs ----
    char* Pb = (char*)Pls;
    float sum[4] = {0.f, 0.f, 0.f, 0.f};
    const unsigned short* Vp = (const unsigned short*)VT
        + ((size_t)bh << 15) + ((size_t)l15 << 9) + l4 * 8;
    int prow   = w * 16 + l15;                 // PV read row
    int prbase = prow << 9;                    // 512 B row stride
    int pswz   = (prow & 7) << 4;
    f32x4 oacc[4] = {};

    #pragma unroll
    for (int half = 0; half < 2; half++) {
        #pragma unroll
        for (int kl = 0; kl < 16; kl++) {
            int kt = half * 16 + kl;
            #pragma unroll
            for (int reg = 0; reg < 4; reg++) {
                float p = __expf(sc[kt][reg] - mx[reg]);
                sum[reg] += p;
                float o = __shfl_xor(p, 1, 64);          // partner column
                unsigned lo = f2b_bits((lane & 1) ? o : p);
                unsigned hi = f2b_bits((lane & 1) ? p : o);
                unsigned pk = lo | (hi << 16);
                if ((lane & 1) == (reg >> 1)) {          // even lanes: reg 0,1; odd: 2,3
                    int row  = w * 16 + l4 * 4 + reg;
                    int byte = (row << 9) + (((kl << 4) + (l15 & ~1)) << 1);
                    byte ^= (row & 7) << 4;
                    *(unsigned*)(Pb + byte) = pk;
                }
            }
        }
        #pragma unroll
        for (int k2 = 0; k2 < 8; k2++) {       // 32 keys per iter
            int pbyte = (prbase + k2 * 64 + l4 * 16) ^ pswz;
            bf16x8 pf = *(const bf16x8*)(Pb + pbyte);
            int kt2 = half * 8 + k2;
            #pragma unroll
            for (int et = 0; et < 4; et++) {
                bf16x8 vf = *(const bf16x8*)(Vp + ((size_t)et << 13) + kt2 * 32);
                oacc[et] = __builtin_amdgcn_mfma_f32_16x16x32_bf16(pf, vf, oacc[et], 0, 0, 0);
            }
        }
    }

    #pragma unroll
    for (int m = 1; m < 16; m <<= 1)
        #pragma unroll
        for (int reg = 0; reg < 4; reg++)
            sum[reg] += __shfl_xor(sum[reg], m, 64);
    float rcp[4];
    #pragma unroll
    for (int reg = 0; reg < 4; reg++) rcp[reg] = 1.0f / sum[reg];

    bf16* op = out + (size_t)(b * SEQ + q0 + w * 16 + l4 * 4) * D_MODEL
             + h * HDIM + l15;
    #pragma unroll
    for (int et = 0; et < 4; et++)
        #pragma unroll
        for (int reg = 0; reg < 4; reg++)
            op[(size_t)reg * D_MODEL + et * 16] = f2b(oacc[et][reg] * rcp[reg]);
}

// ---------------------------------------------------------------------------
// Launch. Inputs fp32 (dict order), OUTPUT fp32 (reference dtype).
// ws peak 105 MiB:
//   [1,7)     wqkv_b     [7,9) wo_b
//   [9,25)    xn -> xn2  (sequential liveness)
//   [25,41)   Q  \
//   [41,57)   K   } -> x1 fp32 [25,57) after attention
//   [57,65)   w1_b       [65,73) w2_b
//   [73,105)  hid bf16 4096x4096 chunk
// d_out (32 MiB fp32) doubles as scratch before final writes:
//   VT bf16 = d_out[0,16M), att bf16 = d_out[16M,32M)
// ---------------------------------------------------------------------------
extern "C" void kernel_launch(void* const* d_in, const int* in_sizes, int n_in,
                              void* d_out, int out_size, void* d_ws, size_t ws_size,
                              hipStream_t stream)
{
    const float* x    = (const float*)d_in[0];
    const float* wqkv = (const float*)d_in[1];
    const float* bqkv = (const float*)d_in[2];
    const float* wo   = (const float*)d_in[3];
    const float* bo   = (const float*)d_in[4];
    const float* relb = (const float*)d_in[5];
    const float* w1   = (const float*)d_in[6];
    const float* b1   = (const float*)d_in[7];
    const float* w2   = (const float*)d_in[8];
    const float* b2   = (const float*)d_in[9];
    const float* ln1w = (const float*)d_in[10];
    const float* ln1b = (const float*)d_in[11];
    const float* ln2w = (const float*)d_in[12];
    const float* ln2b = (const float*)d_in[13];

    char* ws = (char*)d_ws;
    const size_t MB = 1048576;
    bf16*  wqkv_b = (bf16*)(ws + 1 * MB);
    bf16*  wo_b   = (bf16*)(ws + 7 * MB);
    bf16*  xn     = (bf16*)(ws + 9 * MB);
    bf16*  Qb     = (bf16*)(ws + 25 * MB);
    bf16*  Kb     = (bf16*)(ws + 41 * MB);
    float* x1     = (float*)(ws + 25 * MB);  // over dead Q+K, 32 MiB
    bf16*  w1_b   = (bf16*)(ws + 57 * MB);
    bf16*  w2_b   = (bf16*)(ws + 65 * MB);
    bf16*  xn2    = (bf16*)(ws + 9 * MB);    // over dead xn
    bf16*  hid    = (bf16*)(ws + 73 * MB);   // 4096x4096 bf16 chunk
    bf16*  VT     = (bf16*)d_out;                       // d_out[0,16M)
    bf16*  att    = (bf16*)((char*)d_out + 16 * MB);    // d_out[16M,32M)
    float* out    = (float*)d_out;

    // 1. all weights fp32 -> bf16
    cvt_kernel<<<3072, 256, 0, stream>>>(wqkv, wqkv_b, 3 * D_MODEL * D_MODEL);
    cvt_kernel<<<1024, 256, 0, stream>>>(wo,   wo_b,   D_MODEL * D_MODEL);
    cvt_kernel<<<4096, 256, 0, stream>>>(w1,   w1_b,   DFF * D_MODEL);
    cvt_kernel<<<4096, 256, 0, stream>>>(w2,   w2_b,   D_MODEL * DFF);
    // 2. xn = LN1(x)
    ln_kernel<<<MROWS, 256, 0, stream>>>(x, ln1w, ln1b, xn);
    // 3. qkv projection scattered into Q / K / VT(=d_out scratch)
    gemm_bt<3,true><<<dim3(24, 64), 256, 0, stream>>>(xn, wqkv_b, bqkv, nullptr,
        nullptr, Qb, Kb, VT, MROWS, 3 * D_MODEL, D_MODEL);
    // 4. MFMA attention -> att (d_out scratch, bf16)
    attn_mfma<<<dim3(8, 256), 256, 0, stream>>>(Qb, Kb, VT, relb, att);
    // 5. x1 = x + att @ Wo^T + bo   (fp32, over dead Q+K)
    gemm_bt<2,false><<<dim3(8, 64), 256, 0, stream>>>(att, wo_b, bo, x,
        x1, nullptr, nullptr, nullptr, MROWS, D_MODEL, D_MODEL);
    // 6. xn2 = LN2(x1)   (over dead xn)
    ln_kernel<<<MROWS, 256, 0, stream>>>(x1, ln2w, ln2b, xn2);
    // 7/8. FFN in 2 chunks of 4096 rows; final writes fp32 into d_out
    for (int c = 0; c < 2; c++) {
        const bf16*  xc = xn2 + (size_t)c * 4096 * D_MODEL;
        const float* rc = x1  + (size_t)c * 4096 * D_MODEL;
        float*       oc = out + (size_t)c * 4096 * D_MODEL;
        gemm_bt<1,true><<<dim3(32, 32), 256, 0, stream>>>(xc, w1_b, b1, nullptr,
            hid, nullptr, nullptr, nullptr, 4096, DFF, D_MODEL);
        gemm_bt<2,false><<<dim3(8, 32), 256, 0, stream>>>(hid, w2_b, b2, rc,
            oc, nullptr, nullptr, nullptr, 4096, D_MODEL, DFF);
    }
}

// Round 3
// 647.708 us; speedup vs baseline: 1.3977x; 1.3977x over previous
//
#include <hip/hip_runtime.h>
#include <hip/hip_bf16.h>
#include <stdint.h>

typedef __hip_bfloat16 bf16;
typedef __attribute__((ext_vector_type(8))) __bf16 bf16x8;
typedef __attribute__((ext_vector_type(4))) float f32x4;

#define D_MODEL 1024
#define NHEAD   16
#define HDIM    64
#define DFF     4096
#define BATCH   16
#define SEQ     512
#define MROWS   (BATCH*SEQ)   // 8192

__device__ __forceinline__ float b2f_bits(unsigned short u) {
    return __uint_as_float(((unsigned)u) << 16);
}
__device__ __forceinline__ bf16 f2b(float v) { return __float2bfloat16(v); }
__device__ __forceinline__ unsigned short f2b_bits(float v) {
    bf16 t = __float2bfloat16(v);
    return *(unsigned short*)&t;
}
// async global->LDS, 16B per lane (dest = wave-uniform base + lane*16)
__device__ __forceinline__ void gll16(void* lds, const void* gsrc) {
    __builtin_amdgcn_global_load_lds(
        (const __attribute__((address_space(1))) unsigned*)gsrc,
        (__attribute__((address_space(3))) unsigned*)lds,
        16, 0, 0);
}

// ---------------------------------------------------------------------------
// fp32 -> bf16 weight conversion (n multiple of 4; grid covers exactly n/4)
// ---------------------------------------------------------------------------
__global__ __launch_bounds__(256)
void cvt_kernel(const float* __restrict__ in, bf16* __restrict__ out, int n)
{
    int i = (blockIdx.x * 256 + threadIdx.x) * 4;
    if (i >= n) return;
    float4 f = *(const float4*)(in + i);
    ushort4 o;
    o.x = f2b_bits(f.x); o.y = f2b_bits(f.y);
    o.z = f2b_bits(f.z); o.w = f2b_bits(f.w);
    *(ushort4*)((unsigned short*)out + i) = o;
}

// ---------------------------------------------------------------------------
// LayerNorm: fp32 in, bf16 out. One block (256 threads) per row of 1024.
// ---------------------------------------------------------------------------
__global__ __launch_bounds__(256)
void ln_kernel(const float* __restrict__ xin, const float* __restrict__ w,
               const float* __restrict__ b, bf16* __restrict__ out)
{
    int row  = blockIdx.x;
    int t    = threadIdx.x;
    int lane = t & 63, wv = t >> 6;
    int col  = t * 4;

    float4 f = *(const float4*)(xin + (size_t)row * D_MODEL + col);
    float v[4] = {f.x, f.y, f.z, f.w};

    float s  = v[0] + v[1] + v[2] + v[3];
    float ss = v[0]*v[0] + v[1]*v[1] + v[2]*v[2] + v[3]*v[3];
    #pragma unroll
    for (int m = 1; m < 64; m <<= 1) {
        s  += __shfl_xor(s,  m, 64);
        ss += __shfl_xor(ss, m, 64);
    }
    __shared__ float rs0[4], rs1[4];
    if (lane == 0) { rs0[wv] = s; rs1[wv] = ss; }
    __syncthreads();
    s  = rs0[0] + rs0[1] + rs0[2] + rs0[3];
    ss = rs1[0] + rs1[1] + rs1[2] + rs1[3];

    float mu  = s * (1.0f / D_MODEL);
    float var = ss * (1.0f / D_MODEL) - mu * mu;
    float rs  = rsqrtf(var + 1e-5f);

    float4 wf = *(const float4*)(w + col);
    float4 bf = *(const float4*)(b + col);
    ushort4 o;
    o.x = f2b_bits((v[0]-mu)*rs*wf.x + bf.x);
    o.y = f2b_bits((v[1]-mu)*rs*wf.y + bf.y);
    o.z = f2b_bits((v[2]-mu)*rs*wf.z + bf.z);
    o.w = f2b_bits((v[3]-mu)*rs*wf.w + bf.w);
    *(ushort4*)((unsigned short*)out + (size_t)row * D_MODEL + col) = o;
}

// ---------------------------------------------------------------------------
// MFMA GEMM: C[M,N] = A[M,K] * Bw[N,K]^T + bias (fp32). Epilogues:
//   EPI 0: bias -> out            EPI 1: bias + exact GELU -> out
//   EPI 2: bias + fp32 residual -> out
//   EPI 3: bias -> scatter bf16 Q (b,h,s,e) / K (b,h,s,e) / VT (b,h,e,s)
// OUT_B16: store bf16 (internal buffers) vs fp32 (x1 / d_out).
// 128x128 tile, 256 threads (4 waves 2x2), wave = 4x4 mfma_f32_16x16x32_bf16.
// Staging via global_load_lds width=16 (m97 structure): dest = lds + t*16,
// linear [128 rows][32 cols] layout == read layout; 2 barriers per K-step.
// C/D mapping (m89/m91 verified): col = lane&15, row = (lane>>4)*4 + reg.
// M,N multiples of 128; K multiple of 32.
// ---------------------------------------------------------------------------
template<int EPI, bool OUT_B16>
__global__ __launch_bounds__(256)
void gemm_bt(const bf16* __restrict__ A, const bf16* __restrict__ Bw,
             const float* __restrict__ bias, const float* __restrict__ resid,
             void* __restrict__ Cout, bf16* __restrict__ qb,
             bf16* __restrict__ ktb, bf16* __restrict__ vb,
             int M, int N, int K)
{
    int t    = threadIdx.x;
    int lane = t & 63, w = t >> 6;
    int wm   = w & 1,  wn = w >> 1;
    int q    = lane >> 4, r = lane & 15;
    int mb   = blockIdx.y * 128, nb = blockIdx.x * 128;

    __shared__ __bf16 As[128 * 32];
    __shared__ __bf16 Bs[128 * 32];

    f32x4 acc[4][4] = {};

    const char* Ag = (const char*)((const unsigned short*)A + (size_t)mb * K);
    const char* Bg = (const char*)((const unsigned short*)Bw + (size_t)nb * K);

    int ar0 = t >> 2,  ac0 = (t & 3) << 3;   // row, elem-col of this thread's 16B

    for (int k0 = 0; k0 < K; k0 += 32) {
        __syncthreads();   // readers of previous tile done
        size_t off0 = ((size_t)ar0 * K + k0 + ac0) * 2;
        size_t off1 = off0 + (size_t)64 * K * 2;       // +64 rows
        gll16((char*)As + t * 16,        Ag + off0);
        gll16((char*)As + 4096 + t * 16, Ag + off1);
        gll16((char*)Bs + t * 16,        Bg + off0);
        gll16((char*)Bs + 4096 + t * 16, Bg + off1);
        __syncthreads();   // drains vmcnt -> LDS data visible

        bf16x8 af[4], bfr[4];
        #pragma unroll
        for (int i = 0; i < 4; i++)
            af[i] = *(const bf16x8*)(As + (wm * 64 + i * 16 + r) * 32 + q * 8);
        #pragma unroll
        for (int j = 0; j < 4; j++)
            bfr[j] = *(const bf16x8*)(Bs + (wn * 64 + j * 16 + r) * 32 + q * 8);
        #pragma unroll
        for (int i = 0; i < 4; i++)
            #pragma unroll
            for (int j = 0; j < 4; j++)
                acc[i][j] = __builtin_amdgcn_mfma_f32_16x16x32_bf16(af[i], bfr[j], acc[i][j], 0, 0, 0);
    }

    #pragma unroll
    for (int j = 0; j < 4; j++) {
        int n = nb + wn * 64 + j * 16 + r;
        float bv = bias[n];
        #pragma unroll
        for (int i = 0; i < 4; i++) {
            int mbase = mb + wm * 64 + i * 16 + q * 4;
            #pragma unroll
            for (int rr = 0; rr < 4; rr++) {
                int m = mbase + rr;
                float v = acc[i][j][rr] + bv;
                if (EPI == 1) v = 0.5f * v * (1.0f + erff(v * 0.70710678118654752f));
                if (EPI == 2) v += resid[(size_t)m * N + n];
                if (EPI == 3) {
                    int sect = n >> 10;
                    int h = (n >> 6) & 15;
                    int e = n & 63;
                    int bi = m >> 9, s = m & 511;
                    size_t bh = (size_t)bi * NHEAD + h;
                    bf16 val = f2b(v);
                    if (sect == 0)      qb[((bh * SEQ + s) << 6) + e] = val;
                    else if (sect == 1) ktb[((bh * SEQ + s) << 6) + e] = val;  // K rows
                    else                vb[((bh * HDIM + e) << 9) + s] = val;  // V^T
                } else {
                    if (OUT_B16) ((bf16*)Cout)[(size_t)m * N + n] = f2b(v);
                    else         ((float*)Cout)[(size_t)m * N + n] = v;
                }
            }
        }
    }
}

// ---------------------------------------------------------------------------
// MFMA attention. Grid (8,256) -> XCD-swizzled: linear id L, xcd = L&7 (m09
// round-robin); each XCD owns bh in [xcd*32, xcd*32+32), q-tile fastest, so
// K/VT (128 KB/bh) stay L2-resident.
// 256 thr = 4 waves; wave = 16 q-rows x 512 keys. Q,K (b,h,s,64); VT (b,h,64,s).
// P-LDS [64][256] (32 KiB, wave-private rows, XOR-swizzled): PV in two
// 256-key passes reusing the buffer. launch_bounds(256,2): R1 compiled this
// register demand at 104 VGPR no-spill; (256,4) forced a 420 MB scratch spill.
// C/D: col=lane&15, row=(lane>>4)*4+reg (m89/m91 verified).
// ---------------------------------------------------------------------------
__global__ __launch_bounds__(256, 2)
void attn_mfma(const bf16* __restrict__ Q, const bf16* __restrict__ K,
               const bf16* __restrict__ VT, const float* __restrict__ relb,
               bf16* __restrict__ out)
{
    int L   = blockIdx.x + (blockIdx.y << 3);   // grid (8,256) -> L in [0,2048)
    int xcd = L & 7, jj = L >> 3;
    int bh  = xcd * 32 + (jj >> 3);
    int q0  = (jj & 7) * 64;
    int b   = bh >> 4, h = bh & 15;
    int t = threadIdx.x, lane = t & 63, w = t >> 6;
    int l15 = lane & 15, l4 = lane >> 4;

    __shared__ __bf16 Pls[64 * 256];   // 32 KiB, swizzled, wave-private rows
    __shared__ float  rbs[1024];       // rel-bias row for this head

    const float* rb = relb + (size_t)h * (2 * SEQ - 1);
    for (int i = t; i < 2 * SEQ - 1; i += 256) rbs[i] = rb[i];
    __syncthreads();

    // ---- QK^T: 32 key-tiles of 16, 2 MFMAs each ----
    const unsigned short* Qp = (const unsigned short*)Q
        + (((size_t)bh * SEQ + q0 + w * 16 + l15) << 6) + l4 * 8;
    bf16x8 qf0 = *(const bf16x8*)Qp;
    bf16x8 qf1 = *(const bf16x8*)(Qp + 32);

    const unsigned short* Kp = (const unsigned short*)K
        + (((size_t)bh * SEQ + l15) << 6) + l4 * 8;

    f32x4 sc[32];
    #pragma unroll
    for (int kt = 0; kt < 32; kt++) {
        const unsigned short* kp = Kp + ((size_t)kt << 10);  // 16 rows * 64
        bf16x8 kf0 = *(const bf16x8*)kp;
        bf16x8 kf1 = *(const bf16x8*)(kp + 32);
        f32x4 a = {};
        a = __builtin_amdgcn_mfma_f32_16x16x32_bf16(qf0, kf0, a, 0, 0, 0);
        a = __builtin_amdgcn_mfma_f32_16x16x32_bf16(qf1, kf1, a, 0, 0, 0);
        sc[kt] = a;
    }

    // ---- scale + bias + row max ----
    int qbase = q0 + w * 16 + l4 * 4;          // + reg = this lane's rows
    float mx[4] = {-1e30f, -1e30f, -1e30f, -1e30f};
    #pragma unroll
    for (int kt = 0; kt < 32; kt++) {
        int relbase = qbase - (kt * 16 + l15) + (SEQ - 1);
        #pragma unroll
        for (int reg = 0; reg < 4; reg++) {
            float v = sc[kt][reg] * 0.125f + rbs[relbase + reg];
            sc[kt][reg] = v;
            mx[reg] = fmaxf(mx[reg], v);
        }
    }
    #pragma unroll
    for (int m = 1; m < 16; m <<= 1)
        #pragma unroll
        for (int reg = 0; reg < 4; reg++)
            mx[reg] = fmaxf(mx[reg], __shfl_xor(mx[reg], m, 64));

    // ---- two 256-key passes: exp+pack -> swizzled LDS, then PV MFMAs ----
    char* Pb = (char*)Pls;
    float sum[4] = {0.f, 0.f, 0.f, 0.f};
    const unsigned short* Vp = (const unsigned short*)VT
        + ((size_t)bh << 15) + ((size_t)l15 << 9) + l4 * 8;
    int prow   = w * 16 + l15;                 // PV read row
    int prbase = prow << 9;                    // 512 B row stride
    int pswz   = (prow & 7) << 4;
    f32x4 oacc[4] = {};

    #pragma unroll
    for (int half = 0; half < 2; half++) {
        #pragma unroll
        for (int kl = 0; kl < 16; kl++) {
            int kt = half * 16 + kl;
            #pragma unroll
            for (int reg = 0; reg < 4; reg++) {
                float p = __expf(sc[kt][reg] - mx[reg]);
                sum[reg] += p;
                float o = __shfl_xor(p, 1, 64);          // partner column
                unsigned lo = f2b_bits((lane & 1) ? o : p);
                unsigned hi = f2b_bits((lane & 1) ? p : o);
                unsigned pk = lo | (hi << 16);
                if ((lane & 1) == (reg >> 1)) {          // even lanes: reg 0,1; odd: 2,3
                    int row  = w * 16 + l4 * 4 + reg;
                    int byte = (row << 9) + (((kl << 4) + (l15 & ~1)) << 1);
                    byte ^= (row & 7) << 4;
                    *(unsigned*)(Pb + byte) = pk;
                }
            }
        }
        #pragma unroll
        for (int k2 = 0; k2 < 8; k2++) {       // 32 keys per iter
            int pbyte = (prbase + k2 * 64 + l4 * 16) ^ pswz;
            bf16x8 pf = *(const bf16x8*)(Pb + pbyte);
            int kt2 = half * 8 + k2;
            #pragma unroll
            for (int et = 0; et < 4; et++) {
                bf16x8 vf = *(const bf16x8*)(Vp + ((size_t)et << 13) + kt2 * 32);
                oacc[et] = __builtin_amdgcn_mfma_f32_16x16x32_bf16(pf, vf, oacc[et], 0, 0, 0);
            }
        }
    }

    #pragma unroll
    for (int m = 1; m < 16; m <<= 1)
        #pragma unroll
        for (int reg = 0; reg < 4; reg++)
            sum[reg] += __shfl_xor(sum[reg], m, 64);
    float rcp[4];
    #pragma unroll
    for (int reg = 0; reg < 4; reg++) rcp[reg] = 1.0f / sum[reg];

    bf16* op = out + (size_t)(b * SEQ + q0 + w * 16 + l4 * 4) * D_MODEL
             + h * HDIM + l15;
    #pragma unroll
    for (int et = 0; et < 4; et++)
        #pragma unroll
        for (int reg = 0; reg < 4; reg++)
            op[(size_t)reg * D_MODEL + et * 16] = f2b(oacc[et][reg] * rcp[reg]);
}

// ---------------------------------------------------------------------------
// Launch. Inputs fp32 (dict order), OUTPUT fp32 (reference dtype).
// ws peak 121 MiB (<= 128 MiB established):
//   [1,7)     wqkv_b   [7,9) wo_b        (live through step 5)
//   [1,9)     w1_b     (cvt AFTER Wo gemm, over dead wqkv_b+wo_b)
//   [9,25)    xn -> xn2                   (xn2 dead after w1 gemm)
//   [9,17)    w2_b     (cvt AFTER w1 gemm, over dead xn2)
//   [25,41)   Q  \
//   [41,57)   K   } -> x1 fp32 [25,57) after attention (live to the end)
//   [57,121)  hid bf16 8192x4096 (full M: w1 grid 2048 blk, w2 grid 512 blk)
// d_out (32 MiB fp32) doubles as scratch before final writes:
//   VT bf16 = d_out[0,16M), att bf16 = d_out[16M,32M)
// ---------------------------------------------------------------------------
extern "C" void kernel_launch(void* const* d_in, const int* in_sizes, int n_in,
                              void* d_out, int out_size, void* d_ws, size_t ws_size,
                              hipStream_t stream)
{
    const float* x    = (const float*)d_in[0];
    const float* wqkv = (const float*)d_in[1];
    const float* bqkv = (const float*)d_in[2];
    const float* wo   = (const float*)d_in[3];
    const float* bo   = (const float*)d_in[4];
    const float* relb = (const float*)d_in[5];
    const float* w1   = (const float*)d_in[6];
    const float* b1   = (const float*)d_in[7];
    const float* w2   = (const float*)d_in[8];
    const float* b2   = (const float*)d_in[9];
    const float* ln1w = (const float*)d_in[10];
    const float* ln1b = (const float*)d_in[11];
    const float* ln2w = (const float*)d_in[12];
    const float* ln2b = (const float*)d_in[13];

    char* ws = (char*)d_ws;
    const size_t MB = 1048576;
    bf16*  wqkv_b = (bf16*)(ws + 1 * MB);
    bf16*  wo_b   = (bf16*)(ws + 7 * MB);
    bf16*  xn     = (bf16*)(ws + 9 * MB);
    bf16*  Qb     = (bf16*)(ws + 25 * MB);
    bf16*  Kb     = (bf16*)(ws + 41 * MB);
    float* x1     = (float*)(ws + 25 * MB);  // over dead Q+K, 32 MiB
    bf16*  w1_b   = (bf16*)(ws + 1 * MB);    // over dead wqkv_b+wo_b (step 6)
    bf16*  w2_b   = (bf16*)(ws + 9 * MB);    // over dead xn2 (step 9)
    bf16*  xn2    = (bf16*)(ws + 9 * MB);    // over dead xn
    bf16*  hid    = (bf16*)(ws + 57 * MB);   // 8192x4096 bf16, 64 MiB
    bf16*  VT     = (bf16*)d_out;                       // d_out[0,16M)
    bf16*  att    = (bf16*)((char*)d_out + 16 * MB);    // d_out[16M,32M)
    float* out    = (float*)d_out;

    // 1. attention-path weights fp32 -> bf16
    cvt_kernel<<<3072, 256, 0, stream>>>(wqkv, wqkv_b, 3 * D_MODEL * D_MODEL);
    cvt_kernel<<<1024, 256, 0, stream>>>(wo,   wo_b,   D_MODEL * D_MODEL);
    // 2. xn = LN1(x)
    ln_kernel<<<MROWS, 256, 0, stream>>>(x, ln1w, ln1b, xn);
    // 3. qkv projection scattered into Q / K / VT(=d_out scratch)
    gemm_bt<3,true><<<dim3(24, 64), 256, 0, stream>>>(xn, wqkv_b, bqkv, nullptr,
        nullptr, Qb, Kb, VT, MROWS, 3 * D_MODEL, D_MODEL);
    // 4. MFMA attention -> att (d_out scratch, bf16)
    attn_mfma<<<dim3(8, 256), 256, 0, stream>>>(Qb, Kb, VT, relb, att);
    // 5. x1 = x + att @ Wo^T + bo   (fp32, over dead Q+K)
    gemm_bt<2,false><<<dim3(8, 64), 256, 0, stream>>>(att, wo_b, bo, x,
        x1, nullptr, nullptr, nullptr, MROWS, D_MODEL, D_MODEL);
    // 6. w1 -> bf16 (over dead wqkv_b+wo_b)
    cvt_kernel<<<4096, 256, 0, stream>>>(w1, w1_b, DFF * D_MODEL);
    // 7. xn2 = LN2(x1)   (over dead xn)
    ln_kernel<<<MROWS, 256, 0, stream>>>(x1, ln2w, ln2b, xn2);
    // 8. hid = GELU(xn2 @ w1^T + b1), full M: 2048 blocks
    gemm_bt<1,true><<<dim3(32, 64), 256, 0, stream>>>(xn2, w1_b, b1, nullptr,
        hid, nullptr, nullptr, nullptr, MROWS, DFF, D_MODEL);
    // 9. w2 -> bf16 (over dead xn2)
    cvt_kernel<<<4096, 256, 0, stream>>>(w2, w2_b, D_MODEL * DFF);
    // 10. out = x1 + hid @ w2^T + b2, full M: 512 blocks, fp32 into d_out
    gemm_bt<2,false><<<dim3(8, 64), 256, 0, stream>>>(hid, w2_b, b2, x1,
        out, nullptr, nullptr, nullptr, MROWS, D_MODEL, DFF);
}

// Round 5
// 626.235 us; speedup vs baseline: 1.4456x; 1.0343x over previous
//
#include <hip/hip_runtime.h>
#include <hip/hip_bf16.h>
#include <stdint.h>

typedef __hip_bfloat16 bf16;
typedef __attribute__((ext_vector_type(8))) __bf16 bf16x8;
typedef __attribute__((ext_vector_type(4))) float f32x4;

#define D_MODEL 1024
#define NHEAD   16
#define HDIM    64
#define DFF     4096
#define BATCH   16
#define SEQ     512
#define MROWS   (BATCH*SEQ)   // 8192

__device__ __forceinline__ float b2f_bits(unsigned short u) {
    return __uint_as_float(((unsigned)u) << 16);
}
__device__ __forceinline__ bf16 f2b(float v) { return __float2bfloat16(v); }
__device__ __forceinline__ unsigned short f2b_bits(float v) {
    bf16 t = __float2bfloat16(v);
    return *(unsigned short*)&t;
}
// async global->LDS, 16B per lane (dest = wave-uniform base + lane*16)
__device__ __forceinline__ void gll16(void* lds, const void* gsrc) {
    __builtin_amdgcn_global_load_lds(
        (const __attribute__((address_space(1))) unsigned*)gsrc,
        (__attribute__((address_space(3))) unsigned*)lds,
        16, 0, 0);
}

// ---------------------------------------------------------------------------
// fp32 -> bf16 weight conversion (n multiple of 4; grid covers exactly n/4)
// ---------------------------------------------------------------------------
__global__ __launch_bounds__(256)
void cvt_kernel(const float* __restrict__ in, bf16* __restrict__ out, int n)
{
    int i = (blockIdx.x * 256 + threadIdx.x) * 4;
    if (i >= n) return;
    float4 f = *(const float4*)(in + i);
    ushort4 o;
    o.x = f2b_bits(f.x); o.y = f2b_bits(f.y);
    o.z = f2b_bits(f.z); o.w = f2b_bits(f.w);
    *(ushort4*)((unsigned short*)out + i) = o;
}

// ---------------------------------------------------------------------------
// LayerNorm: fp32 in, bf16 out. One block (256 threads) per row of 1024.
// ---------------------------------------------------------------------------
__global__ __launch_bounds__(256)
void ln_kernel(const float* __restrict__ xin, const float* __restrict__ w,
               const float* __restrict__ b, bf16* __restrict__ out)
{
    int row  = blockIdx.x;
    int t    = threadIdx.x;
    int lane = t & 63, wv = t >> 6;
    int col  = t * 4;

    float4 f = *(const float4*)(xin + (size_t)row * D_MODEL + col);
    float v[4] = {f.x, f.y, f.z, f.w};

    float s  = v[0] + v[1] + v[2] + v[3];
    float ss = v[0]*v[0] + v[1]*v[1] + v[2]*v[2] + v[3]*v[3];
    #pragma unroll
    for (int m = 1; m < 64; m <<= 1) {
        s  += __shfl_xor(s,  m, 64);
        ss += __shfl_xor(ss, m, 64);
    }
    __shared__ float rs0[4], rs1[4];
    if (lane == 0) { rs0[wv] = s; rs1[wv] = ss; }
    __syncthreads();
    s  = rs0[0] + rs0[1] + rs0[2] + rs0[3];
    ss = rs1[0] + rs1[1] + rs1[2] + rs1[3];

    float mu  = s * (1.0f / D_MODEL);
    float var = ss * (1.0f / D_MODEL) - mu * mu;
    float rs  = rsqrtf(var + 1e-5f);

    float4 wf = *(const float4*)(w + col);
    float4 bf = *(const float4*)(b + col);
    ushort4 o;
    o.x = f2b_bits((v[0]-mu)*rs*wf.x + bf.x);
    o.y = f2b_bits((v[1]-mu)*rs*wf.y + bf.y);
    o.z = f2b_bits((v[2]-mu)*rs*wf.z + bf.z);
    o.w = f2b_bits((v[3]-mu)*rs*wf.w + bf.w);
    *(ushort4*)((unsigned short*)out + (size_t)row * D_MODEL + col) = o;
}

// ---------------------------------------------------------------------------
// MFMA GEMM: C[M,N] = A[M,K] * Bw[N,K]^T + bias (fp32). Epilogues:
//   EPI 0: bias -> out            EPI 1: bias + exact GELU -> out
//   EPI 2: bias + fp32 residual -> out
//   EPI 3: bias -> scatter bf16 Q (b,h,s,e) / K (b,h,s,e) / VT (b,h,e,s)
// OUT_B16: store bf16 (internal buffers) vs fp32 (x1 / d_out).
// 128x128 tile, 256 threads (4 waves 2x2), wave = 4x4 mfma_f32_16x16x32_bf16.
// Staging via global_load_lds width=16 (m97 structure); 2 barriers per K-step.
// XCD-aware block remap (T1): nwg%8==0 for all launches -> bijective chunked
// map, each XCD owns a contiguous range of row-major tile ids (L2 locality).
// C/D mapping (m89/m91 verified): col = lane&15, row = (lane>>4)*4 + reg.
// M,N multiples of 128; K multiple of 32. nwg must be divisible by 8.
// ---------------------------------------------------------------------------
template<int EPI, bool OUT_B16>
__global__ __launch_bounds__(256)
void gemm_bt(const bf16* __restrict__ A, const bf16* __restrict__ Bw,
             const float* __restrict__ bias, const float* __restrict__ resid,
             void* __restrict__ Cout, bf16* __restrict__ qb,
             bf16* __restrict__ ktb, bf16* __restrict__ vb,
             int M, int N, int K)
{
    int t    = threadIdx.x;
    int lane = t & 63, w = t >> 6;
    int wm   = w & 1,  wn = w >> 1;
    int q    = lane >> 4, r = lane & 15;

    // XCD swizzle: dispatch index L round-robins L&7 over XCDs (m09);
    // give each XCD a contiguous chunk of the original tile ordering.
    int gx  = gridDim.x;
    int L   = blockIdx.y * gx + blockIdx.x;
    int qq  = (gx * gridDim.y) >> 3;
    int nid = (L & 7) * qq + (L >> 3);
    int mb  = (nid / gx) * 128, nb = (nid % gx) * 128;

    __shared__ __bf16 As[128 * 32];
    __shared__ __bf16 Bs[128 * 32];

    f32x4 acc[4][4] = {};

    const char* Ag = (const char*)((const unsigned short*)A + (size_t)mb * K);
    const char* Bg = (const char*)((const unsigned short*)Bw + (size_t)nb * K);

    int ar0 = t >> 2,  ac0 = (t & 3) << 3;   // row, elem-col of this thread's 16B

    for (int k0 = 0; k0 < K; k0 += 32) {
        __syncthreads();   // readers of previous tile done
        size_t off0 = ((size_t)ar0 * K + k0 + ac0) * 2;
        size_t off1 = off0 + (size_t)64 * K * 2;       // +64 rows
        gll16((char*)As + t * 16,        Ag + off0);
        gll16((char*)As + 4096 + t * 16, Ag + off1);
        gll16((char*)Bs + t * 16,        Bg + off0);
        gll16((char*)Bs + 4096 + t * 16, Bg + off1);
        __syncthreads();   // drains vmcnt -> LDS data visible

        bf16x8 af[4], bfr[4];
        #pragma unroll
        for (int i = 0; i < 4; i++)
            af[i] = *(const bf16x8*)(As + (wm * 64 + i * 16 + r) * 32 + q * 8);
        #pragma unroll
        for (int j = 0; j < 4; j++)
            bfr[j] = *(const bf16x8*)(Bs + (wn * 64 + j * 16 + r) * 32 + q * 8);
        #pragma unroll
        for (int i = 0; i < 4; i++)
            #pragma unroll
            for (int j = 0; j < 4; j++)
                acc[i][j] = __builtin_amdgcn_mfma_f32_16x16x32_bf16(af[i], bfr[j], acc[i][j], 0, 0, 0);
    }

    #pragma unroll
    for (int j = 0; j < 4; j++) {
        int n = nb + wn * 64 + j * 16 + r;
        float bv = bias[n];
        #pragma unroll
        for (int i = 0; i < 4; i++) {
            int mbase = mb + wm * 64 + i * 16 + q * 4;
            #pragma unroll
            for (int rr = 0; rr < 4; rr++) {
                int m = mbase + rr;
                float v = acc[i][j][rr] + bv;
                if (EPI == 1) v = 0.5f * v * (1.0f + erff(v * 0.70710678118654752f));
                if (EPI == 2) v += resid[(size_t)m * N + n];
                if (EPI == 3) {
                    int sect = n >> 10;
                    int h = (n >> 6) & 15;
                    int e = n & 63;
                    int bi = m >> 9, s = m & 511;
                    size_t bh = (size_t)bi * NHEAD + h;
                    bf16 val = f2b(v);
                    if (sect == 0)      qb[((bh * SEQ + s) << 6) + e] = val;
                    else if (sect == 1) ktb[((bh * SEQ + s) << 6) + e] = val;  // K rows
                    else                vb[((bh * HDIM + e) << 9) + s] = val;  // V^T
                } else {
                    if (OUT_B16) ((bf16*)Cout)[(size_t)m * N + n] = f2b(v);
                    else         ((float*)Cout)[(size_t)m * N + n] = v;
                }
            }
        }
    }
}

// ---------------------------------------------------------------------------
// MFMA attention, chunked. Grid (8,256) XCD-swizzled (bh chunks per XCD; K/VT
// L2-resident -> R3 measured FETCH 25 MB). 256 thr = 4 waves; wave = 16 q-rows.
// Keys processed in 4 chunks of 128: QK MFMAs -> bias+exp+sum (NO max pass:
// |scores| <~ 10 << 88, fp32 exp safe; softmax is shift-invariant) -> pack
// bf16 pairs into wave-private XOR-swizzled P-chunk LDS -> PV MFMAs.
// Live state ~110 VGPR (sc[8]=32 not sc[32]=128) -> launch_bounds(256,4),
// 4 blocks/CU, LDS 20.5 KB. #pragma unroll 1 on chunk loop caps registers.
// C/D: col=lane&15, row=(lane>>4)*4+reg (m89/m91 verified).
// ---------------------------------------------------------------------------
__global__ __launch_bounds__(256, 4)
void attn_mfma(const bf16* __restrict__ Q, const bf16* __restrict__ K,
               const bf16* __restrict__ VT, const float* __restrict__ relb,
               bf16* __restrict__ out)
{
    int L   = blockIdx.x + (blockIdx.y << 3);   // grid (8,256) -> L in [0,2048)
    int xcd = L & 7, jj = L >> 3;
    int bh  = xcd * 32 + (jj >> 3);
    int q0  = (jj & 7) * 64;
    int b   = bh >> 4, h = bh & 15;
    int t = threadIdx.x, lane = t & 63, w = t >> 6;
    int l15 = lane & 15, l4 = lane >> 4;

    __shared__ __bf16 Pls[64 * 128];   // 16 KiB P-chunk, swizzled, wave-private rows
    __shared__ float  rbs[1024];       // rel-bias row for this head

    const float* rb = relb + (size_t)h * (2 * SEQ - 1);
    for (int i = t; i < 2 * SEQ - 1; i += 256) rbs[i] = rb[i];
    __syncthreads();

    // Q fragments (16 rows per wave)
    const unsigned short* Qp = (const unsigned short*)Q
        + (((size_t)bh * SEQ + q0 + w * 16 + l15) << 6) + l4 * 8;
    bf16x8 qf0 = *(const bf16x8*)Qp;
    bf16x8 qf1 = *(const bf16x8*)(Qp + 32);

    const unsigned short* Kp = (const unsigned short*)K
        + (((size_t)bh * SEQ + l15) << 6) + l4 * 8;
    const unsigned short* Vp = (const unsigned short*)VT
        + ((size_t)bh << 15) + ((size_t)l15 << 9) + l4 * 8;

    char* Pb = (char*)Pls;
    int qbase  = q0 + w * 16 + l4 * 4;         // + reg = this lane's score rows
    int prow   = w * 16 + l15;                 // PV read row
    int prbase = prow << 8;                    // 256 B row stride
    int pswz   = (prow & 7) << 4;
    float sum[4] = {0.f, 0.f, 0.f, 0.f};
    f32x4 oacc[4] = {};

    #pragma unroll 1
    for (int c = 0; c < 4; c++) {
        // ---- QK^T for this 128-key chunk: 8 key-tiles of 16 ----
        f32x4 sc[8];
        #pragma unroll
        for (int kl = 0; kl < 8; kl++) {
            const unsigned short* kp = Kp + ((size_t)(c * 8 + kl) << 10);
            bf16x8 kf0 = *(const bf16x8*)kp;
            bf16x8 kf1 = *(const bf16x8*)(kp + 32);
            f32x4 a = {};
            a = __builtin_amdgcn_mfma_f32_16x16x32_bf16(qf0, kf0, a, 0, 0, 0);
            a = __builtin_amdgcn_mfma_f32_16x16x32_bf16(qf1, kf1, a, 0, 0, 0);
            sc[kl] = a;
        }
        // ---- bias + exp + sum + pack -> swizzled LDS (wave-private rows) ----
        #pragma unroll
        for (int kl = 0; kl < 8; kl++) {
            int relbase = qbase - ((c * 8 + kl) * 16 + l15) + (SEQ - 1);
            #pragma unroll
            for (int reg = 0; reg < 4; reg++) {
                float p = __expf(sc[kl][reg] * 0.125f + rbs[relbase + reg]);
                sum[reg] += p;
                float o = __shfl_xor(p, 1, 64);          // partner column
                unsigned lo = f2b_bits((lane & 1) ? o : p);
                unsigned hi = f2b_bits((lane & 1) ? p : o);
                unsigned pk = lo | (hi << 16);
                if ((lane & 1) == (reg >> 1)) {          // even lanes: reg 0,1; odd: 2,3
                    int row  = w * 16 + l4 * 4 + reg;
                    int byte = (row << 8) + (((kl << 4) + (l15 & ~1)) << 1);
                    byte ^= (row & 7) << 4;
                    *(unsigned*)(Pb + byte) = pk;
                }
            }
        }
        // ---- PV for this chunk: 4 k-steps of 32 keys ----
        #pragma unroll
        for (int k2 = 0; k2 < 4; k2++) {
            int pbyte = (prbase + k2 * 64 + l4 * 16) ^ pswz;
            bf16x8 pf = *(const bf16x8*)(Pb + pbyte);
            int kt2 = c * 4 + k2;
            #pragma unroll
            for (int et = 0; et < 4; et++) {
                bf16x8 vf = *(const bf16x8*)(Vp + ((size_t)et << 13) + kt2 * 32);
                oacc[et] = __builtin_amdgcn_mfma_f32_16x16x32_bf16(pf, vf, oacc[et], 0, 0, 0);
            }
        }
    }

    #pragma unroll
    for (int m = 1; m < 16; m <<= 1)
        #pragma unroll
        for (int reg = 0; reg < 4; reg++)
            sum[reg] += __shfl_xor(sum[reg], m, 64);
    float rcp[4];
    #pragma unroll
    for (int reg = 0; reg < 4; reg++) rcp[reg] = 1.0f / sum[reg];

    bf16* op = out + (size_t)(b * SEQ + q0 + w * 16 + l4 * 4) * D_MODEL
             + h * HDIM + l15;
    #pragma unroll
    for (int et = 0; et < 4; et++)
        #pragma unroll
        for (int reg = 0; reg < 4; reg++)
            op[(size_t)reg * D_MODEL + et * 16] = f2b(oacc[et][reg] * rcp[reg]);
}

// ---------------------------------------------------------------------------
// Launch. Inputs fp32 (dict order), OUTPUT fp32 (reference dtype).
// ws peak 121 MiB (<= 128 MiB established):
//   [1,7)     wqkv_b   [7,9) wo_b        (live through step 5)
//   [1,9)     w1_b     (cvt AFTER Wo gemm, over dead wqkv_b+wo_b)
//   [9,25)    xn -> xn2                   (xn2 dead after w1 gemm)
//   [9,17)    w2_b     (cvt AFTER w1 gemm, over dead xn2)
//   [25,41)   Q  \
//   [41,57)   K   } -> x1 fp32 [25,57) after attention (live to the end)
//   [57,121)  hid bf16 8192x4096 (full M: w1 grid 2048 blk, w2 grid 512 blk)
// d_out (32 MiB fp32) doubles as scratch before final writes:
//   VT bf16 = d_out[0,16M), att bf16 = d_out[16M,32M)
// ---------------------------------------------------------------------------
extern "C" void kernel_launch(void* const* d_in, const int* in_sizes, int n_in,
                              void* d_out, int out_size, void* d_ws, size_t ws_size,
                              hipStream_t stream)
{
    const float* x    = (const float*)d_in[0];
    const float* wqkv = (const float*)d_in[1];
    const float* bqkv = (const float*)d_in[2];
    const float* wo   = (const float*)d_in[3];
    const float* bo   = (const float*)d_in[4];
    const float* relb = (const float*)d_in[5];
    const float* w1   = (const float*)d_in[6];
    const float* b1   = (const float*)d_in[7];
    const float* w2   = (const float*)d_in[8];
    const float* b2   = (const float*)d_in[9];
    const float* ln1w = (const float*)d_in[10];
    const float* ln1b = (const float*)d_in[11];
    const float* ln2w = (const float*)d_in[12];
    const float* ln2b = (const float*)d_in[13];

    char* ws = (char*)d_ws;
    const size_t MB = 1048576;
    bf16*  wqkv_b = (bf16*)(ws + 1 * MB);
    bf16*  wo_b   = (bf16*)(ws + 7 * MB);
    bf16*  xn     = (bf16*)(ws + 9 * MB);
    bf16*  Qb     = (bf16*)(ws + 25 * MB);
    bf16*  Kb     = (bf16*)(ws + 41 * MB);
    float* x1     = (float*)(ws + 25 * MB);  // over dead Q+K, 32 MiB
    bf16*  w1_b   = (bf16*)(ws + 1 * MB);    // over dead wqkv_b+wo_b (step 6)
    bf16*  w2_b   = (bf16*)(ws + 9 * MB);    // over dead xn2 (step 9)
    bf16*  xn2    = (bf16*)(ws + 9 * MB);    // over dead xn
    bf16*  hid    = (bf16*)(ws + 57 * MB);   // 8192x4096 bf16, 64 MiB
    bf16*  VT     = (bf16*)d_out;                       // d_out[0,16M)
    bf16*  att    = (bf16*)((char*)d_out + 16 * MB);    // d_out[16M,32M)
    float* out    = (float*)d_out;

    // 1. attention-path weights fp32 -> bf16
    cvt_kernel<<<3072, 256, 0, stream>>>(wqkv, wqkv_b, 3 * D_MODEL * D_MODEL);
    cvt_kernel<<<1024, 256, 0, stream>>>(wo,   wo_b,   D_MODEL * D_MODEL);
    // 2. xn = LN1(x)
    ln_kernel<<<MROWS, 256, 0, stream>>>(x, ln1w, ln1b, xn);
    // 3. qkv projection scattered into Q / K / VT(=d_out scratch)
    gemm_bt<3,true><<<dim3(24, 64), 256, 0, stream>>>(xn, wqkv_b, bqkv, nullptr,
        nullptr, Qb, Kb, VT, MROWS, 3 * D_MODEL, D_MODEL);
    // 4. MFMA attention -> att (d_out scratch, bf16)
    attn_mfma<<<dim3(8, 256), 256, 0, stream>>>(Qb, Kb, VT, relb, att);
    // 5. x1 = x + att @ Wo^T + bo   (fp32, over dead Q+K)
    gemm_bt<2,false><<<dim3(8, 64), 256, 0, stream>>>(att, wo_b, bo, x,
        x1, nullptr, nullptr, nullptr, MROWS, D_MODEL, D_MODEL);
    // 6. w1 -> bf16 (over dead wqkv_b+wo_b)
    cvt_kernel<<<4096, 256, 0, stream>>>(w1, w1_b, DFF * D_MODEL);
    // 7. xn2 = LN2(x1)   (over dead xn)
    ln_kernel<<<MROWS, 256, 0, stream>>>(x1, ln2w, ln2b, xn2);
    // 8. hid = GELU(xn2 @ w1^T + b1), full M: 2048 blocks
    gemm_bt<1,true><<<dim3(32, 64), 256, 0, stream>>>(xn2, w1_b, b1, nullptr,
        hid, nullptr, nullptr, nullptr, MROWS, DFF, D_MODEL);
    // 9. w2 -> bf16 (over dead xn2)
    cvt_kernel<<<4096, 256, 0, stream>>>(w2, w2_b, D_MODEL * DFF);
    // 10. out = x1 + hid @ w2^T + b2, full M: 512 blocks, fp32 into d_out
    gemm_bt<2,false><<<dim3(8, 64), 256, 0, stream>>>(hid, w2_b, b2, x1,
        out, nullptr, nullptr, nullptr, MROWS, D_MODEL, DFF);
}

// Round 6
// 568.712 us; speedup vs baseline: 1.5918x; 1.1011x over previous
//
#include <hip/hip_runtime.h>
#include <hip/hip_bf16.h>
#include <stdint.h>

typedef __hip_bfloat16 bf16;
typedef __attribute__((ext_vector_type(8))) __bf16 bf16x8;
typedef __attribute__((ext_vector_type(4))) float f32x4;

#define D_MODEL 1024
#define NHEAD   16
#define HDIM    64
#define DFF     4096
#define BATCH   16
#define SEQ     512
#define MROWS   (BATCH*SEQ)   // 8192

__device__ __forceinline__ float b2f_bits(unsigned short u) {
    return __uint_as_float(((unsigned)u) << 16);
}
__device__ __forceinline__ bf16 f2b(float v) { return __float2bfloat16(v); }
__device__ __forceinline__ unsigned short f2b_bits(float v) {
    bf16 t = __float2bfloat16(v);
    return *(unsigned short*)&t;
}
// async global->LDS, 16B per lane (dest = wave-uniform base + lane*16)
__device__ __forceinline__ void gll16(void* lds, const void* gsrc) {
    __builtin_amdgcn_global_load_lds(
        (const __attribute__((address_space(1))) unsigned*)gsrc,
        (__attribute__((address_space(3))) unsigned*)lds,
        16, 0, 0);
}
// exact-enough GELU: tanh form, max |err| ~3e-4 vs erf form (ok at bf16 out)
__device__ __forceinline__ float gelu_f(float u) {
    float z  = 0.7978845608028654f * (u + 0.044715f * u * u * u);
    float az = fabsf(z);
    float e  = __expf(-2.0f * az);
    float th = (1.0f - e) / (1.0f + e);
    th = copysignf(th, z);
    return 0.5f * u * (1.0f + th);
}

// ---------------------------------------------------------------------------
// fp32 -> bf16 weight conversion (n multiple of 4; grid covers exactly n/4)
// ---------------------------------------------------------------------------
__global__ __launch_bounds__(256)
void cvt_kernel(const float* __restrict__ in, bf16* __restrict__ out, int n)
{
    int i = (blockIdx.x * 256 + threadIdx.x) * 4;
    if (i >= n) return;
    float4 f = *(const float4*)(in + i);
    ushort4 o;
    o.x = f2b_bits(f.x); o.y = f2b_bits(f.y);
    o.z = f2b_bits(f.z); o.w = f2b_bits(f.w);
    *(ushort4*)((unsigned short*)out + i) = o;
}

// ---------------------------------------------------------------------------
// LayerNorm: fp32 in, bf16 out. One block (256 threads) per row of 1024.
// ---------------------------------------------------------------------------
__global__ __launch_bounds__(256)
void ln_kernel(const float* __restrict__ xin, const float* __restrict__ w,
               const float* __restrict__ b, bf16* __restrict__ out)
{
    int row  = blockIdx.x;
    int t    = threadIdx.x;
    int lane = t & 63, wv = t >> 6;
    int col  = t * 4;

    float4 f = *(const float4*)(xin + (size_t)row * D_MODEL + col);
    float v[4] = {f.x, f.y, f.z, f.w};

    float s  = v[0] + v[1] + v[2] + v[3];
    float ss = v[0]*v[0] + v[1]*v[1] + v[2]*v[2] + v[3]*v[3];
    #pragma unroll
    for (int m = 1; m < 64; m <<= 1) {
        s  += __shfl_xor(s,  m, 64);
        ss += __shfl_xor(ss, m, 64);
    }
    __shared__ float rs0[4], rs1[4];
    if (lane == 0) { rs0[wv] = s; rs1[wv] = ss; }
    __syncthreads();
    s  = rs0[0] + rs0[1] + rs0[2] + rs0[3];
    ss = rs1[0] + rs1[1] + rs1[2] + rs1[3];

    float mu  = s * (1.0f / D_MODEL);
    float var = ss * (1.0f / D_MODEL) - mu * mu;
    float rs  = rsqrtf(var + 1e-5f);

    float4 wf = *(const float4*)(w + col);
    float4 bf = *(const float4*)(b + col);
    ushort4 o;
    o.x = f2b_bits((v[0]-mu)*rs*wf.x + bf.x);
    o.y = f2b_bits((v[1]-mu)*rs*wf.y + bf.y);
    o.z = f2b_bits((v[2]-mu)*rs*wf.z + bf.z);
    o.w = f2b_bits((v[3]-mu)*rs*wf.w + bf.w);
    *(ushort4*)((unsigned short*)out + (size_t)row * D_MODEL + col) = o;
}

// ---------------------------------------------------------------------------
// MFMA GEMM: C[M,N] = A[M,K] * Bw[N,K]^T + bias (fp32). Epilogues:
//   EPI 0: bias -> out            EPI 1: bias + fast GELU -> out
//   EPI 2: bias + fp32 residual -> out
//   EPI 3: bias -> scatter bf16 Q (b,h,s,e) / K (b,h,s,e) / VT (b,h,e,s)
// OUT_B16: store bf16 (internal buffers) vs fp32 (x1 / d_out).
// 128x128 tile, 256 threads (4 waves 2x2), wave = 4x4 mfma_f32_16x16x32_bf16.
// 2-PHASE staging (T3-minimum): double-buffered 2x16KB LDS; iteration tt
// issues global_load_lds for tile tt+1 into buf^1 BEFORE ds_read+MFMA of
// buf; single __syncthreads per K-step (= vmcnt(0)+lgkmcnt(0)+barrier drain:
// next tile landed, current tile's reads retired).
// bf16 C-path stages the 128x128 C-tile through the freed 32KB LDS and
// copies out 16B/lane full rows (kills the 32B-segment 2x writeback amp).
// XCD-aware block remap (T1): nwg%8==0 -> bijective chunked map.
// C/D mapping (m89/m91 verified): col = lane&15, row = (lane>>4)*4 + reg.
// M,N multiples of 128; K multiple of 32. nwg must be divisible by 8.
// ---------------------------------------------------------------------------
template<int EPI, bool OUT_B16>
__global__ __launch_bounds__(256)
void gemm_bt(const bf16* __restrict__ A, const bf16* __restrict__ Bw,
             const float* __restrict__ bias, const float* __restrict__ resid,
             void* __restrict__ Cout, bf16* __restrict__ qb,
             bf16* __restrict__ ktb, bf16* __restrict__ vb,
             int M, int N, int K)
{
    int t    = threadIdx.x;
    int lane = t & 63, w = t >> 6;
    int wm   = w & 1,  wn = w >> 1;
    int q    = lane >> 4, r = lane & 15;

    // XCD swizzle: dispatch index L round-robins L&7 over XCDs (m09);
    // give each XCD a contiguous chunk of the original tile ordering.
    int gx  = gridDim.x;
    int L   = blockIdx.y * gx + blockIdx.x;
    int qq  = (gx * gridDim.y) >> 3;
    int nid = (L & 7) * qq + (L >> 3);
    int mb  = (nid / gx) * 128, nb = (nid % gx) * 128;

    // buf c: A at smem+c*16384 (8KB), B at +8192. C-stage reuses all 32KB.
    __shared__ char smem[32768];

    f32x4 acc[4][4] = {};

    const char* Ag = (const char*)((const unsigned short*)A + (size_t)mb * K);
    const char* Bg = (const char*)((const unsigned short*)Bw + (size_t)nb * K);

    int ar0 = t >> 2,  ac0 = (t & 3) << 3;   // row, elem-col of this thread's 16B

    int nt = K >> 5;

    #define STAGE(c, k0) do {                                      \
        char* dA = smem + (c) * 16384;                             \
        char* dB = dA + 8192;                                      \
        size_t off0 = ((size_t)ar0 * K + (k0) + ac0) * 2;          \
        size_t off1 = off0 + (size_t)64 * K * 2;                   \
        gll16(dA + t * 16,        Ag + off0);                      \
        gll16(dA + 4096 + t * 16, Ag + off1);                      \
        gll16(dB + t * 16,        Bg + off0);                      \
        gll16(dB + 4096 + t * 16, Bg + off1);                      \
    } while (0)

    STAGE(0, 0);
    __syncthreads();

    int cur = 0;
    for (int tt = 0; tt < nt; ++tt) {
        if (tt + 1 < nt) STAGE(cur ^ 1, (tt + 1) << 5);   // prefetch next tile

        const __bf16* Asb = (const __bf16*)(smem + cur * 16384);
        const __bf16* Bsb = Asb + 4096;
        bf16x8 af[4], bfr[4];
        #pragma unroll
        for (int i = 0; i < 4; i++)
            af[i] = *(const bf16x8*)(Asb + (wm * 64 + i * 16 + r) * 32 + q * 8);
        #pragma unroll
        for (int j = 0; j < 4; j++)
            bfr[j] = *(const bf16x8*)(Bsb + (wn * 64 + j * 16 + r) * 32 + q * 8);
        #pragma unroll
        for (int i = 0; i < 4; i++)
            #pragma unroll
            for (int j = 0; j < 4; j++)
                acc[i][j] = __builtin_amdgcn_mfma_f32_16x16x32_bf16(af[i], bfr[j], acc[i][j], 0, 0, 0);

        __syncthreads();   // drains vmcnt (next tile ready) + lgkm (reads done)
        cur ^= 1;
    }
    #undef STAGE

    if (OUT_B16 && EPI != 3) {
        // stage C-tile bf16 in LDS, copy out coalesced (256B rows, 16B/lane)
        __bf16* Cs = (__bf16*)smem;
        #pragma unroll
        for (int j = 0; j < 4; j++) {
            int n = nb + wn * 64 + j * 16 + r;
            float bv = bias[n];
            #pragma unroll
            for (int i = 0; i < 4; i++) {
                #pragma unroll
                for (int rr = 0; rr < 4; rr++) {
                    float v = acc[i][j][rr] + bv;
                    if (EPI == 1) v = gelu_f(v);
                    if (EPI == 2) v += resid[(size_t)(mb + wm*64 + i*16 + q*4 + rr) * N + n];
                    Cs[(wm*64 + i*16 + q*4 + rr) * 128 + wn*64 + j*16 + r] = *(__bf16*)&(unsigned short&)*(unsigned short[]){f2b_bits(v)};
                }
            }
        }
        __syncthreads();
        char* Cg = (char*)Cout;
        #pragma unroll
        for (int c = 0; c < 8; c++) {
            int idx = t + c * 256;           // 2048 chunks: row = idx>>4, 16B ch
            int row = idx >> 4, ch = idx & 15;
            *(int4*)(Cg + ((size_t)(mb + row) * N + nb) * 2 + ch * 16) =
                *(const int4*)((const char*)Cs + row * 256 + ch * 16);
        }
    } else {
        #pragma unroll
        for (int j = 0; j < 4; j++) {
            int n = nb + wn * 64 + j * 16 + r;
            float bv = bias[n];
            #pragma unroll
            for (int i = 0; i < 4; i++) {
                int mbase = mb + wm * 64 + i * 16 + q * 4;
                #pragma unroll
                for (int rr = 0; rr < 4; rr++) {
                    int m = mbase + rr;
                    float v = acc[i][j][rr] + bv;
                    if (EPI == 1) v = gelu_f(v);
                    if (EPI == 2) v += resid[(size_t)m * N + n];
                    if (EPI == 3) {
                        int sect = n >> 10;
                        int h = (n >> 6) & 15;
                        int e = n & 63;
                        int bi = m >> 9, s = m & 511;
                        size_t bh = (size_t)bi * NHEAD + h;
                        bf16 val = f2b(v);
                        if (sect == 0)      qb[((bh * SEQ + s) << 6) + e] = val;
                        else if (sect == 1) ktb[((bh * SEQ + s) << 6) + e] = val;  // K rows
                        else                vb[((bh * HDIM + e) << 9) + s] = val;  // V^T
                    } else {
                        if (OUT_B16) ((bf16*)Cout)[(size_t)m * N + n] = f2b(v);
                        else         ((float*)Cout)[(size_t)m * N + n] = v;
                    }
                }
            }
        }
    }
}

// ---------------------------------------------------------------------------
// MFMA attention, chunked. Grid (8,256) XCD-swizzled (bh chunks per XCD; K/VT
// L2-resident -> R3 measured FETCH 25 MB). 256 thr = 4 waves; wave = 16 q-rows.
// Keys processed in 4 chunks of 128: QK MFMAs -> bias+exp+sum (NO max pass:
// |scores| <~ 10 << 88, fp32 exp safe; softmax is shift-invariant) -> pack
// bf16 pairs into wave-private XOR-swizzled P-chunk LDS -> PV MFMAs.
// Live state ~110 VGPR (sc[8]=32 not sc[32]=128) -> launch_bounds(256,4),
// 4 blocks/CU, LDS 20.5 KB. #pragma unroll 1 on chunk loop caps registers.
// C/D: col=lane&15, row=(lane>>4)*4+reg (m89/m91 verified).
// ---------------------------------------------------------------------------
__global__ __launch_bounds__(256, 4)
void attn_mfma(const bf16* __restrict__ Q, const bf16* __restrict__ K,
               const bf16* __restrict__ VT, const float* __restrict__ relb,
               bf16* __restrict__ out)
{
    int L   = blockIdx.x + (blockIdx.y << 3);   // grid (8,256) -> L in [0,2048)
    int xcd = L & 7, jj = L >> 3;
    int bh  = xcd * 32 + (jj >> 3);
    int q0  = (jj & 7) * 64;
    int b   = bh >> 4, h = bh & 15;
    int t = threadIdx.x, lane = t & 63, w = t >> 6;
    int l15 = lane & 15, l4 = lane >> 4;

    __shared__ __bf16 Pls[64 * 128];   // 16 KiB P-chunk, swizzled, wave-private rows
    __shared__ float  rbs[1024];       // rel-bias row for this head

    const float* rb = relb + (size_t)h * (2 * SEQ - 1);
    for (int i = t; i < 2 * SEQ - 1; i += 256) rbs[i] = rb[i];
    __syncthreads();

    // Q fragments (16 rows per wave)
    const unsigned short* Qp = (const unsigned short*)Q
        + (((size_t)bh * SEQ + q0 + w * 16 + l15) << 6) + l4 * 8;
    bf16x8 qf0 = *(const bf16x8*)Qp;
    bf16x8 qf1 = *(const bf16x8*)(Qp + 32);

    const unsigned short* Kp = (const unsigned short*)K
        + (((size_t)bh * SEQ + l15) << 6) + l4 * 8;
    const unsigned short* Vp = (const unsigned short*)VT
        + ((size_t)bh << 15) + ((size_t)l15 << 9) + l4 * 8;

    char* Pb = (char*)Pls;
    int qbase  = q0 + w * 16 + l4 * 4;         // + reg = this lane's score rows
    int prow   = w * 16 + l15;                 // PV read row
    int prbase = prow << 8;                    // 256 B row stride
    int pswz   = (prow & 7) << 4;
    float sum[4] = {0.f, 0.f, 0.f, 0.f};
    f32x4 oacc[4] = {};

    #pragma unroll 1
    for (int c = 0; c < 4; c++) {
        // ---- QK^T for this 128-key chunk: 8 key-tiles of 16 ----
        f32x4 sc[8];
        #pragma unroll
        for (int kl = 0; kl < 8; kl++) {
            const unsigned short* kp = Kp + ((size_t)(c * 8 + kl) << 10);
            bf16x8 kf0 = *(const bf16x8*)kp;
            bf16x8 kf1 = *(const bf16x8*)(kp + 32);
            f32x4 a = {};
            a = __builtin_amdgcn_mfma_f32_16x16x32_bf16(qf0, kf0, a, 0, 0, 0);
            a = __builtin_amdgcn_mfma_f32_16x16x32_bf16(qf1, kf1, a, 0, 0, 0);
            sc[kl] = a;
        }
        // ---- bias + exp + sum + pack -> swizzled LDS (wave-private rows) ----
        #pragma unroll
        for (int kl = 0; kl < 8; kl++) {
            int relbase = qbase - ((c * 8 + kl) * 16 + l15) + (SEQ - 1);
            #pragma unroll
            for (int reg = 0; reg < 4; reg++) {
                float p = __expf(sc[kl][reg] * 0.125f + rbs[relbase + reg]);
                sum[reg] += p;
                float o = __shfl_xor(p, 1, 64);          // partner column
                unsigned lo = f2b_bits((lane & 1) ? o : p);
                unsigned hi = f2b_bits((lane & 1) ? p : o);
                unsigned pk = lo | (hi << 16);
                if ((lane & 1) == (reg >> 1)) {          // even lanes: reg 0,1; odd: 2,3
                    int row  = w * 16 + l4 * 4 + reg;
                    int byte = (row << 8) + (((kl << 4) + (l15 & ~1)) << 1);
                    byte ^= (row & 7) << 4;
                    *(unsigned*)(Pb + byte) = pk;
                }
            }
        }
        // ---- PV for this chunk: 4 k-steps of 32 keys ----
        #pragma unroll
        for (int k2 = 0; k2 < 4; k2++) {
            int pbyte = (prbase + k2 * 64 + l4 * 16) ^ pswz;
            bf16x8 pf = *(const bf16x8*)(Pb + pbyte);
            int kt2 = c * 4 + k2;
            #pragma unroll
            for (int et = 0; et < 4; et++) {
                bf16x8 vf = *(const bf16x8*)(Vp + ((size_t)et << 13) + kt2 * 32);
                oacc[et] = __builtin_amdgcn_mfma_f32_16x16x32_bf16(pf, vf, oacc[et], 0, 0, 0);
            }
        }
    }

    #pragma unroll
    for (int m = 1; m < 16; m <<= 1)
        #pragma unroll
        for (int reg = 0; reg < 4; reg++)
            sum[reg] += __shfl_xor(sum[reg], m, 64);
    float rcp[4];
    #pragma unroll
    for (int reg = 0; reg < 4; reg++) rcp[reg] = 1.0f / sum[reg];

    bf16* op = out + (size_t)(b * SEQ + q0 + w * 16 + l4 * 4) * D_MODEL
             + h * HDIM + l15;
    #pragma unroll
    for (int et = 0; et < 4; et++)
        #pragma unroll
        for (int reg = 0; reg < 4; reg++)
            op[(size_t)reg * D_MODEL + et * 16] = f2b(oacc[et][reg] * rcp[reg]);
}

// ---------------------------------------------------------------------------
// Launch. Inputs fp32 (dict order), OUTPUT fp32 (reference dtype).
// ws peak 121 MiB (<= 128 MiB established):
//   [1,7)     wqkv_b   [7,9) wo_b        (live through step 5)
//   [1,9)     w1_b     (cvt AFTER Wo gemm, over dead wqkv_b+wo_b)
//   [9,25)    xn -> xn2                   (xn2 dead after w1 gemm)
//   [9,17)    w2_b     (cvt AFTER w1 gemm, over dead xn2)
//   [25,41)   Q  \
//   [41,57)   K   } -> x1 fp32 [25,57) after attention (live to the end)
//   [57,121)  hid bf16 8192x4096 (full M: w1 grid 2048 blk, w2 grid 512 blk)
// d_out (32 MiB fp32) doubles as scratch before final writes:
//   VT bf16 = d_out[0,16M), att bf16 = d_out[16M,32M)
// ---------------------------------------------------------------------------
extern "C" void kernel_launch(void* const* d_in, const int* in_sizes, int n_in,
                              void* d_out, int out_size, void* d_ws, size_t ws_size,
                              hipStream_t stream)
{
    const float* x    = (const float*)d_in[0];
    const float* wqkv = (const float*)d_in[1];
    const float* bqkv = (const float*)d_in[2];
    const float* wo   = (const float*)d_in[3];
    const float* bo   = (const float*)d_in[4];
    const float* relb = (const float*)d_in[5];
    const float* w1   = (const float*)d_in[6];
    const float* b1   = (const float*)d_in[7];
    const float* w2   = (const float*)d_in[8];
    const float* b2   = (const float*)d_in[9];
    const float* ln1w = (const float*)d_in[10];
    const float* ln1b = (const float*)d_in[11];
    const float* ln2w = (const float*)d_in[12];
    const float* ln2b = (const float*)d_in[13];

    char* ws = (char*)d_ws;
    const size_t MB = 1048576;
    bf16*  wqkv_b = (bf16*)(ws + 1 * MB);
    bf16*  wo_b   = (bf16*)(ws + 7 * MB);
    bf16*  xn     = (bf16*)(ws + 9 * MB);
    bf16*  Qb     = (bf16*)(ws + 25 * MB);
    bf16*  Kb     = (bf16*)(ws + 41 * MB);
    float* x1     = (float*)(ws + 25 * MB);  // over dead Q+K, 32 MiB
    bf16*  w1_b   = (bf16*)(ws + 1 * MB);    // over dead wqkv_b+wo_b (step 6)
    bf16*  w2_b   = (bf16*)(ws + 9 * MB);    // over dead xn2 (step 9)
    bf16*  xn2    = (bf16*)(ws + 9 * MB);    // over dead xn
    bf16*  hid    = (bf16*)(ws + 57 * MB);   // 8192x4096 bf16, 64 MiB
    bf16*  VT     = (bf16*)d_out;                       // d_out[0,16M)
    bf16*  att    = (bf16*)((char*)d_out + 16 * MB);    // d_out[16M,32M)
    float* out    = (float*)d_out;

    // 1. attention-path weights fp32 -> bf16
    cvt_kernel<<<3072, 256, 0, stream>>>(wqkv, wqkv_b, 3 * D_MODEL * D_MODEL);
    cvt_kernel<<<1024, 256, 0, stream>>>(wo,   wo_b,   D_MODEL * D_MODEL);
    // 2. xn = LN1(x)
    ln_kernel<<<MROWS, 256, 0, stream>>>(x, ln1w, ln1b, xn);
    // 3. qkv projection scattered into Q / K / VT(=d_out scratch)
    gemm_bt<3,true><<<dim3(24, 64), 256, 0, stream>>>(xn, wqkv_b, bqkv, nullptr,
        nullptr, Qb, Kb, VT, MROWS, 3 * D_MODEL, D_MODEL);
    // 4. MFMA attention -> att (d_out scratch, bf16)
    attn_mfma<<<dim3(8, 256), 256, 0, stream>>>(Qb, Kb, VT, relb, att);
    // 5. x1 = x + att @ Wo^T + bo   (fp32, over dead Q+K)
    gemm_bt<2,false><<<dim3(8, 64), 256, 0, stream>>>(att, wo_b, bo, x,
        x1, nullptr, nullptr, nullptr, MROWS, D_MODEL, D_MODEL);
    // 6. w1 -> bf16 (over dead wqkv_b+wo_b)
    cvt_kernel<<<4096, 256, 0, stream>>>(w1, w1_b, DFF * D_MODEL);
    // 7. xn2 = LN2(x1)   (over dead xn)
    ln_kernel<<<MROWS, 256, 0, stream>>>(x1, ln2w, ln2b, xn2);
    // 8. hid = GELU(xn2 @ w1^T + b1), full M: 2048 blocks
    gemm_bt<1,true><<<dim3(32, 64), 256, 0, stream>>>(xn2, w1_b, b1, nullptr,
        hid, nullptr, nullptr, nullptr, MROWS, DFF, D_MODEL);
    // 9. w2 -> bf16 (over dead xn2)
    cvt_kernel<<<4096, 256, 0, stream>>>(w2, w2_b, D_MODEL * DFF);
    // 10. out = x1 + hid @ w2^T + b2, full M: 512 blocks, fp32 into d_out
    gemm_bt<2,false><<<dim3(8, 64), 256, 0, stream>>>(hid, w2_b, b2, x1,
        out, nullptr, nullptr, nullptr, MROWS, D_MODEL, DFF);
}

// Round 8
// 518.402 us; speedup vs baseline: 1.7463x; 1.0970x over previous
//
#include <hip/hip_runtime.h>
#include <hip/hip_bf16.h>
#include <stdint.h>

typedef __hip_bfloat16 bf16;
typedef __attribute__((ext_vector_type(8))) __bf16 bf16x8;
typedef __attribute__((ext_vector_type(4))) float f32x4;

#define D_MODEL 1024
#define NHEAD   16
#define HDIM    64
#define DFF     4096
#define BATCH   16
#define SEQ     512
#define MROWS   (BATCH*SEQ)   // 8192

__device__ __forceinline__ float b2f_bits(unsigned short u) {
    return __uint_as_float(((unsigned)u) << 16);
}
__device__ __forceinline__ bf16 f2b(float v) { return __float2bfloat16(v); }
__device__ __forceinline__ unsigned short f2b_bits(float v) {
    bf16 t = __float2bfloat16(v);
    return *(unsigned short*)&t;
}
// async global->LDS, 16B per lane (dest = wave-uniform base + lane*16)
__device__ __forceinline__ void gll16(void* lds, const void* gsrc) {
    __builtin_amdgcn_global_load_lds(
        (const __attribute__((address_space(1))) unsigned*)gsrc,
        (__attribute__((address_space(3))) unsigned*)lds,
        16, 0, 0);
}
// exact-enough GELU: tanh form, max |err| ~3e-4 vs erf form (ok at bf16 out)
__device__ __forceinline__ float gelu_f(float u) {
    float z  = 0.7978845608028654f * (u + 0.044715f * u * u * u);
    float az = fabsf(z);
    float e  = __expf(-2.0f * az);
    float th = (1.0f - e) / (1.0f + e);
    th = copysignf(th, z);
    return 0.5f * u * (1.0f + th);
}

// ---------------------------------------------------------------------------
// fp32 -> bf16 weight conversion (n multiple of 4; grid covers exactly n/4)
// ---------------------------------------------------------------------------
__global__ __launch_bounds__(256)
void cvt_kernel(const float* __restrict__ in, bf16* __restrict__ out, int n)
{
    int i = (blockIdx.x * 256 + threadIdx.x) * 4;
    if (i >= n) return;
    float4 f = *(const float4*)(in + i);
    ushort4 o;
    o.x = f2b_bits(f.x); o.y = f2b_bits(f.y);
    o.z = f2b_bits(f.z); o.w = f2b_bits(f.w);
    *(ushort4*)((unsigned short*)out + i) = o;
}

// ---------------------------------------------------------------------------
// LayerNorm: fp32 in, bf16 out. One block (256 threads) per row of 1024.
// ---------------------------------------------------------------------------
__global__ __launch_bounds__(256)
void ln_kernel(const float* __restrict__ xin, const float* __restrict__ w,
               const float* __restrict__ b, bf16* __restrict__ out)
{
    int row  = blockIdx.x;
    int t    = threadIdx.x;
    int lane = t & 63, wv = t >> 6;
    int col  = t * 4;

    float4 f = *(const float4*)(xin + (size_t)row * D_MODEL + col);
    float v[4] = {f.x, f.y, f.z, f.w};

    float s  = v[0] + v[1] + v[2] + v[3];
    float ss = v[0]*v[0] + v[1]*v[1] + v[2]*v[2] + v[3]*v[3];
    #pragma unroll
    for (int m = 1; m < 64; m <<= 1) {
        s  += __shfl_xor(s,  m, 64);
        ss += __shfl_xor(ss, m, 64);
    }
    __shared__ float rs0[4], rs1[4];
    if (lane == 0) { rs0[wv] = s; rs1[wv] = ss; }
    __syncthreads();
    s  = rs0[0] + rs0[1] + rs0[2] + rs0[3];
    ss = rs1[0] + rs1[1] + rs1[2] + rs1[3];

    float mu  = s * (1.0f / D_MODEL);
    float var = ss * (1.0f / D_MODEL) - mu * mu;
    float rs  = rsqrtf(var + 1e-5f);

    float4 wf = *(const float4*)(w + col);
    float4 bf = *(const float4*)(b + col);
    ushort4 o;
    o.x = f2b_bits((v[0]-mu)*rs*wf.x + bf.x);
    o.y = f2b_bits((v[1]-mu)*rs*wf.y + bf.y);
    o.z = f2b_bits((v[2]-mu)*rs*wf.z + bf.z);
    o.w = f2b_bits((v[3]-mu)*rs*wf.w + bf.w);
    *(ushort4*)((unsigned short*)out + (size_t)row * D_MODEL + col) = o;
}

// ---------------------------------------------------------------------------
// MFMA GEMM: C[M,N] = A[M,K] * Bw[N,K]^T + bias (fp32). Epilogues:
//   EPI 0: bias -> out            EPI 1: bias + fast GELU -> out
//   EPI 2: bias + fp32 residual -> out
//   EPI 3: bias -> scatter bf16 Q (b,h,s,e) / K (b,h,s,e) / VT (b,h,e,s)
// OUT_B16: store bf16 (internal buffers) vs fp32 (x1 / d_out).
// 128x128 tile, 256 threads (4 waves 2x2), wave = 4x4 mfma_f32_16x16x32_bf16.
// 2-PHASE staging: double-buffered 2x16KB LDS; single barrier per K-step.
// bf16 C-path stages C-tile through LDS, copies out 16B/lane full rows.
// XCD-aware block remap (T1): nwg%8==0 -> bijective chunked map.
// C/D mapping (m89/m91 verified): col = lane&15, row = (lane>>4)*4 + reg.
// M,N multiples of 128; K multiple of 32. nwg must be divisible by 8.
// ---------------------------------------------------------------------------
template<int EPI, bool OUT_B16>
__global__ __launch_bounds__(256)
void gemm_bt(const bf16* __restrict__ A, const bf16* __restrict__ Bw,
             const float* __restrict__ bias, const float* __restrict__ resid,
             void* __restrict__ Cout, bf16* __restrict__ qb,
             bf16* __restrict__ ktb, bf16* __restrict__ vb,
             int M, int N, int K)
{
    int t    = threadIdx.x;
    int lane = t & 63, w = t >> 6;
    int wm   = w & 1,  wn = w >> 1;
    int q    = lane >> 4, r = lane & 15;

    // XCD swizzle: dispatch index L round-robins L&7 over XCDs (m09);
    // give each XCD a contiguous chunk of the original tile ordering.
    int gx  = gridDim.x;
    int L   = blockIdx.y * gx + blockIdx.x;
    int qq  = (gx * gridDim.y) >> 3;
    int nid = (L & 7) * qq + (L >> 3);
    int mb  = (nid / gx) * 128, nb = (nid % gx) * 128;

    // buf c: A at smem+c*16384 (8KB), B at +8192. C-stage reuses all 32KB.
    __shared__ char smem[32768];

    f32x4 acc[4][4] = {};

    const char* Ag = (const char*)((const unsigned short*)A + (size_t)mb * K);
    const char* Bg = (const char*)((const unsigned short*)Bw + (size_t)nb * K);

    int ar0 = t >> 2,  ac0 = (t & 3) << 3;   // row, elem-col of this thread's 16B

    int nt = K >> 5;

    #define STAGE(c, k0) do {                                      \
        char* dA = smem + (c) * 16384;                             \
        char* dB = dA + 8192;                                      \
        size_t off0 = ((size_t)ar0 * K + (k0) + ac0) * 2;          \
        size_t off1 = off0 + (size_t)64 * K * 2;                   \
        gll16(dA + t * 16,        Ag + off0);                      \
        gll16(dA + 4096 + t * 16, Ag + off1);                      \
        gll16(dB + t * 16,        Bg + off0);                      \
        gll16(dB + 4096 + t * 16, Bg + off1);                      \
    } while (0)

    STAGE(0, 0);
    __syncthreads();

    int cur = 0;
    for (int tt = 0; tt < nt; ++tt) {
        if (tt + 1 < nt) STAGE(cur ^ 1, (tt + 1) << 5);   // prefetch next tile

        const __bf16* Asb = (const __bf16*)(smem + cur * 16384);
        const __bf16* Bsb = Asb + 4096;
        bf16x8 af[4], bfr[4];
        #pragma unroll
        for (int i = 0; i < 4; i++)
            af[i] = *(const bf16x8*)(Asb + (wm * 64 + i * 16 + r) * 32 + q * 8);
        #pragma unroll
        for (int j = 0; j < 4; j++)
            bfr[j] = *(const bf16x8*)(Bsb + (wn * 64 + j * 16 + r) * 32 + q * 8);
        #pragma unroll
        for (int i = 0; i < 4; i++)
            #pragma unroll
            for (int j = 0; j < 4; j++)
                acc[i][j] = __builtin_amdgcn_mfma_f32_16x16x32_bf16(af[i], bfr[j], acc[i][j], 0, 0, 0);

        __syncthreads();   // drains vmcnt (next tile ready) + lgkm (reads done)
        cur ^= 1;
    }
    #undef STAGE

    if (OUT_B16 && EPI != 3) {
        // stage C-tile bf16 in LDS, copy out coalesced (256B rows, 16B/lane)
        __bf16* Cs = (__bf16*)smem;
        #pragma unroll
        for (int j = 0; j < 4; j++) {
            int n = nb + wn * 64 + j * 16 + r;
            float bv = bias[n];
            #pragma unroll
            for (int i = 0; i < 4; i++) {
                #pragma unroll
                for (int rr = 0; rr < 4; rr++) {
                    float v = acc[i][j][rr] + bv;
                    if (EPI == 1) v = gelu_f(v);
                    if (EPI == 2) v += resid[(size_t)(mb + wm*64 + i*16 + q*4 + rr) * N + n];
                    unsigned short ub = f2b_bits(v);
                    Cs[(wm*64 + i*16 + q*4 + rr) * 128 + wn*64 + j*16 + r] = *(__bf16*)&ub;
                }
            }
        }
        __syncthreads();
        char* Cg = (char*)Cout;
        #pragma unroll
        for (int c = 0; c < 8; c++) {
            int idx = t + c * 256;           // 2048 chunks: row = idx>>4, 16B ch
            int row = idx >> 4, ch = idx & 15;
            *(int4*)(Cg + ((size_t)(mb + row) * N + nb) * 2 + ch * 16) =
                *(const int4*)((const char*)Cs + row * 256 + ch * 16);
        }
    } else {
        #pragma unroll
        for (int j = 0; j < 4; j++) {
            int n = nb + wn * 64 + j * 16 + r;
            float bv = bias[n];
            #pragma unroll
            for (int i = 0; i < 4; i++) {
                int mbase = mb + wm * 64 + i * 16 + q * 4;
                #pragma unroll
                for (int rr = 0; rr < 4; rr++) {
                    int m = mbase + rr;
                    float v = acc[i][j][rr] + bv;
                    if (EPI == 1) v = gelu_f(v);
                    if (EPI == 2) v += resid[(size_t)m * N + n];
                    if (EPI == 3) {
                        int sect = n >> 10;
                        int h = (n >> 6) & 15;
                        int e = n & 63;
                        int bi = m >> 9, s = m & 511;
                        size_t bh = (size_t)bi * NHEAD + h;
                        bf16 val = f2b(v);
                        if (sect == 0)      qb[((bh * SEQ + s) << 6) + e] = val;
                        else if (sect == 1) ktb[((bh * SEQ + s) << 6) + e] = val;  // K rows
                        else                vb[((bh * HDIM + e) << 9) + s] = val;  // V^T
                    } else {
                        if (OUT_B16) ((bf16*)Cout)[(size_t)m * N + n] = f2b(v);
                        else         ((float*)Cout)[(size_t)m * N + n] = v;
                    }
                }
            }
        }
    }
}

// ---------------------------------------------------------------------------
// MFMA attention, LDS-pipelined. Grid (8,256) XCD-swizzled (K/VT L2-resident,
// R3: FETCH 25 MB). 256 thr = 4 waves; wave = 16 q-rows; keys in 8 chunks
// of 64. Per chunk: cooperatively DMA-stage (global_load_lds: ZERO data
// VGPRs -> load depth not register-limited, unlike R6 whose 64-VGPR compile
// serialized per-wave loads) chunk c+1 K [64k][64e] + V^T [64e][64s] into
// the spare 16KB buffer, compute chunk c from LDS, one uniform barrier.
// 128B-row tiles are 16-way bank conflicts if linear (G4); fix per rule #21:
// linear DMA dest + pre-swizzled global source (granule j ^= row&7) +
// swizzled ds_read (byte ^= (row&7)<<4) -- same involution both sides.
// Softmax: one-pass no-max (|s| <~ 10 << 88 fp32 exp overflow), P packed
// bf16 into wave-private swizzled [64][64] LDS tile.
// LDS 44KB -> 3 blocks/CU; launch_bounds(256,3) for VGPR headroom.
// C/D: col=lane&15, row=(lane>>4)*4+reg (m89/m91 verified).
// ---------------------------------------------------------------------------
__global__ __launch_bounds__(256, 3)
void attn_mfma(const bf16* __restrict__ Q, const bf16* __restrict__ K,
               const bf16* __restrict__ VT, const float* __restrict__ relb,
               bf16* __restrict__ out)
{
    int L   = blockIdx.x + (blockIdx.y << 3);   // grid (8,256) -> L in [0,2048)
    int xcd = L & 7, jj = L >> 3;
    int bh  = xcd * 32 + (jj >> 3);
    int q0  = (jj & 7) * 64;
    int b   = bh >> 4, h = bh & 15;
    int t = threadIdx.x, lane = t & 63, w = t >> 6;
    int l15 = lane & 15, l4 = lane >> 4;

    __shared__ int4  kvbuf4[2048];   // 32 KiB: 2 x (K-chunk 8KB + V-chunk 8KB)
    __shared__ int4  Pls4[512];      //  8 KiB P-tile [64 q][64 k], swizzled
    __shared__ float rbs[1024];      //  4 KiB rel-bias row for this head

    char* kv = (char*)kvbuf4;
    char* Pb = (char*)Pls4;
    const char* Kg = (const char*)K  + ((size_t)bh << 16);
    const char* Vg = (const char*)VT + ((size_t)bh << 16);

    // stage chunk (c) into buffer (bs): K rows (s=c*64+r, 128B) and V^T rows
    // (e=r, s-slice c*64.., 128B); source granule pre-swizzled j ^= (r&7).
    #define STAGE_KV(bs, c) do {                                              \
        char* kd = kv + (bs) * 16384;                                         \
        char* vd = kd + 8192;                                                 \
        _Pragma("unroll")                                                     \
        for (int i = 0; i < 2; i++) {                                         \
            int g = t + i * 256;                                              \
            int rr_ = g >> 3;                                                 \
            int jj_ = (g & 7) ^ (rr_ & 7);                                    \
            gll16(kd + g * 16,                                                \
                  Kg + (((size_t)(c) * 64 + rr_) << 7) + (jj_ << 4));         \
            gll16(vd + g * 16,                                                \
                  Vg + ((size_t)rr_ << 10) + ((size_t)(c) << 7) + (jj_ << 4));\
        }                                                                     \
    } while (0)

    const float* rb = relb + (size_t)h * (2 * SEQ - 1);
    for (int i = t; i < 2 * SEQ - 1; i += 256) rbs[i] = rb[i];
    STAGE_KV(0, 0);

    // Q fragments (16 rows per wave), loaded while stage 0 is in flight
    const unsigned short* Qp = (const unsigned short*)Q
        + (((size_t)bh * SEQ + q0 + w * 16 + l15) << 6) + l4 * 8;
    bf16x8 qf0 = *(const bf16x8*)Qp;
    bf16x8 qf1 = *(const bf16x8*)(Qp + 32);

    __syncthreads();   // stage 0 + rbs visible

    int qbase  = q0 + w * 16 + l4 * 4;         // + reg = this lane's score rows
    int prow   = w * 16 + l15;                 // PV A-frag read row
    int prbase = prow << 7;                    // 128 B row stride
    int pswz   = (prow & 7) << 4;
    float sum[4] = {0.f, 0.f, 0.f, 0.f};
    f32x4 oacc[4] = {};

    int cur = 0;
    for (int c = 0; c < 8; ++c) {
        if (c < 7) STAGE_KV(cur ^ 1, c + 1);   // DMA next chunk (no VGPRs)

        const char* Kl = kv + cur * 16384;
        const char* Vl = Kl + 8192;

        // ---- QK^T: 4 key-tiles of 16, 2 MFMAs each (K=64) ----
        f32x4 sc[4];
        #pragma unroll
        for (int kt = 0; kt < 4; kt++) {
            int row = kt * 16 + l15;
            int swz = (row & 7) << 4;
            bf16x8 kf0 = *(const bf16x8*)(Kl + (((row << 7) + (l4 << 4)) ^ swz));
            bf16x8 kf1 = *(const bf16x8*)(Kl + (((row << 7) + 64 + (l4 << 4)) ^ swz));
            f32x4 a = {};
            a = __builtin_amdgcn_mfma_f32_16x16x32_bf16(qf0, kf0, a, 0, 0, 0);
            a = __builtin_amdgcn_mfma_f32_16x16x32_bf16(qf1, kf1, a, 0, 0, 0);
            sc[kt] = a;
        }

        // ---- bias + exp + sum + pack -> swizzled P (wave-private rows) ----
        #pragma unroll
        for (int kt = 0; kt < 4; kt++) {
            int relbase = qbase - (c * 64 + kt * 16 + l15) + (SEQ - 1);
            #pragma unroll
            for (int reg = 0; reg < 4; reg++) {
                float p = __expf(sc[kt][reg] * 0.125f + rbs[relbase + reg]);
                sum[reg] += p;
                float o = __shfl_xor(p, 1, 64);          // partner column
                unsigned lo = f2b_bits((lane & 1) ? o : p);
                unsigned hi = f2b_bits((lane & 1) ? p : o);
                unsigned pk = lo | (hi << 16);
                if ((lane & 1) == (reg >> 1)) {          // even lanes: reg 0,1; odd: 2,3
                    int row  = w * 16 + l4 * 4 + reg;
                    int byte = ((row << 7) + (kt << 5) + ((l15 & ~1) << 1))
                             ^ ((row & 7) << 4);
                    *(unsigned*)(Pb + byte) = pk;
                }
            }
        }

        // ---- PV: 2 k-slices of 32 keys x 4 e-tiles ----
        #pragma unroll
        for (int k2 = 0; k2 < 2; k2++) {
            int pbyte = (prbase + (k2 << 6) + (l4 << 4)) ^ pswz;
            bf16x8 pf = *(const bf16x8*)(Pb + pbyte);
            #pragma unroll
            for (int et = 0; et < 4; et++) {
                int vrow = et * 16 + l15;
                bf16x8 vf = *(const bf16x8*)
                    (Vl + (((vrow << 7) + (k2 << 6) + (l4 << 4)) ^ ((vrow & 7) << 4)));
                oacc[et] = __builtin_amdgcn_mfma_f32_16x16x32_bf16(pf, vf, oacc[et], 0, 0, 0);
            }
        }

        __syncthreads();   // stage c+1 landed; all waves done reading buf cur
        cur ^= 1;
    }
    #undef STAGE_KV

    #pragma unroll
    for (int m = 1; m < 16; m <<= 1)
        #pragma unroll
        for (int reg = 0; reg < 4; reg++)
            sum[reg] += __shfl_xor(sum[reg], m, 64);
    float rcp[4];
    #pragma unroll
    for (int reg = 0; reg < 4; reg++) rcp[reg] = 1.0f / sum[reg];

    bf16* op = out + (size_t)(b * SEQ + q0 + w * 16 + l4 * 4) * D_MODEL
             + h * HDIM + l15;
    #pragma unroll
    for (int et = 0; et < 4; et++)
        #pragma unroll
        for (int reg = 0; reg < 4; reg++)
            op[(size_t)reg * D_MODEL + et * 16] = f2b(oacc[et][reg] * rcp[reg]);
}

// ---------------------------------------------------------------------------
// Launch. Inputs fp32 (dict order), OUTPUT fp32 (reference dtype).
// ws peak 121 MiB (<= 128 MiB established):
//   [1,7)     wqkv_b   [7,9) wo_b        (live through step 5)
//   [1,9)     w1_b     (cvt AFTER Wo gemm, over dead wqkv_b+wo_b)
//   [9,25)    xn -> xn2                   (xn2 dead after w1 gemm)
//   [9,17)    w2_b     (cvt AFTER w1 gemm, over dead xn2)
//   [25,41)   Q  \
//   [41,57)   K   } -> x1 fp32 [25,57) after attention (live to the end)
//   [57,121)  hid bf16 8192x4096 (full M: w1 grid 2048 blk, w2 grid 512 blk)
// d_out (32 MiB fp32) doubles as scratch before final writes:
//   VT bf16 = d_out[0,16M), att bf16 = d_out[16M,32M)
// ---------------------------------------------------------------------------
extern "C" void kernel_launch(void* const* d_in, const int* in_sizes, int n_in,
                              void* d_out, int out_size, void* d_ws, size_t ws_size,
                              hipStream_t stream)
{
    const float* x    = (const float*)d_in[0];
    const float* wqkv = (const float*)d_in[1];
    const float* bqkv = (const float*)d_in[2];
    const float* wo   = (const float*)d_in[3];
    const float* bo   = (const float*)d_in[4];
    const float* relb = (const float*)d_in[5];
    const float* w1   = (const float*)d_in[6];
    const float* b1   = (const float*)d_in[7];
    const float* w2   = (const float*)d_in[8];
    const float* b2   = (const float*)d_in[9];
    const float* ln1w = (const float*)d_in[10];
    const float* ln1b = (const float*)d_in[11];
    const float* ln2w = (const float*)d_in[12];
    const float* ln2b = (const float*)d_in[13];

    char* ws = (char*)d_ws;
    const size_t MB = 1048576;
    bf16*  wqkv_b = (bf16*)(ws + 1 * MB);
    bf16*  wo_b   = (bf16*)(ws + 7 * MB);
    bf16*  xn     = (bf16*)(ws + 9 * MB);
    bf16*  Qb     = (bf16*)(ws + 25 * MB);
    bf16*  Kb     = (bf16*)(ws + 41 * MB);
    float* x1     = (float*)(ws + 25 * MB);  // over dead Q+K, 32 MiB
    bf16*  w1_b   = (bf16*)(ws + 1 * MB);    // over dead wqkv_b+wo_b (step 6)
    bf16*  w2_b   = (bf16*)(ws + 9 * MB);    // over dead xn2 (step 9)
    bf16*  xn2    = (bf16*)(ws + 9 * MB);    // over dead xn
    bf16*  hid    = (bf16*)(ws + 57 * MB);   // 8192x4096 bf16, 64 MiB
    bf16*  VT     = (bf16*)d_out;                       // d_out[0,16M)
    bf16*  att    = (bf16*)((char*)d_out + 16 * MB);    // d_out[16M,32M)
    float* out    = (float*)d_out;

    // 1. attention-path weights fp32 -> bf16
    cvt_kernel<<<3072, 256, 0, stream>>>(wqkv, wqkv_b, 3 * D_MODEL * D_MODEL);
    cvt_kernel<<<1024, 256, 0, stream>>>(wo,   wo_b,   D_MODEL * D_MODEL);
    // 2. xn = LN1(x)
    ln_kernel<<<MROWS, 256, 0, stream>>>(x, ln1w, ln1b, xn);
    // 3. qkv projection scattered into Q / K / VT(=d_out scratch)
    gemm_bt<3,true><<<dim3(24, 64), 256, 0, stream>>>(xn, wqkv_b, bqkv, nullptr,
        nullptr, Qb, Kb, VT, MROWS, 3 * D_MODEL, D_MODEL);
    // 4. MFMA attention -> att (d_out scratch, bf16)
    attn_mfma<<<dim3(8, 256), 256, 0, stream>>>(Qb, Kb, VT, relb, att);
    // 5. x1 = x + att @ Wo^T + bo   (fp32, over dead Q+K)
    gemm_bt<2,false><<<dim3(8, 64), 256, 0, stream>>>(att, wo_b, bo, x,
        x1, nullptr, nullptr, nullptr, MROWS, D_MODEL, D_MODEL);
    // 6. w1 -> bf16 (over dead wqkv_b+wo_b)
    cvt_kernel<<<4096, 256, 0, stream>>>(w1, w1_b, DFF * D_MODEL);
    // 7. xn2 = LN2(x1)   (over dead xn)
    ln_kernel<<<MROWS, 256, 0, stream>>>(x1, ln2w, ln2b, xn2);
    // 8. hid = GELU(xn2 @ w1^T + b1), full M: 2048 blocks
    gemm_bt<1,true><<<dim3(32, 64), 256, 0, stream>>>(xn2, w1_b, b1, nullptr,
        hid, nullptr, nullptr, nullptr, MROWS, DFF, D_MODEL);
    // 9. w2 -> bf16 (over dead xn2)
    cvt_kernel<<<4096, 256, 0, stream>>>(w2, w2_b, D_MODEL * DFF);
    // 10. out = x1 + hid @ w2^T + b2, full M: 512 blocks, fp32 into d_out
    gemm_bt<2,false><<<dim3(8, 64), 256, 0, stream>>>(hid, w2_b, b2, x1,
        out, nullptr, nullptr, nullptr, MROWS, D_MODEL, DFF);
}